// Round 14
// baseline (143.920 us; speedup 1.0000x reference)
//
#include <hip/hip_runtime.h>

// SelfAttention_33852932227207 — MI355X, round 14.
// e = x^T (Wq^T Wa Wk) x / sqrt(512);  out = softmax(e) @ (x (Wb Wv)^T).
// r7/r8/r9/r13: four k_proj structures, all 44 µs, nothing saturated ->
// fixed per-tile overhead (stage drain + barrier resync ~2300cy) vs 2060cy
// MFMA at BK=64. r14: k_proj BK=128 (8 tiles not 16) -> MFMA window 4100cy,
// overhead fraction halves. A(256x128,64KB) single-buf; B(128x128) dbuf
// 2x32KB = 128KB LDS. Stage order A(j+1) then B(j+2) last -> vmcnt(4) drains
// A(j+1)+B(j+1), B(j+2) flies under next compute. k-order unchanged ->
// bit-identical. ONLY k_proj changed vs r13.

typedef __attribute__((ext_vector_type(8))) short b16x8;
typedef __attribute__((ext_vector_type(4))) float f4;
typedef unsigned short u16;

#define DEVINL __device__ __forceinline__

DEVINL u16 f2bf(float f) {               // fp32 -> bf16 RNE
  unsigned int u = __float_as_uint(f);
  u = u + 0x7FFFu + ((u >> 16) & 1u);
  return (u16)(u >> 16);
}
DEVINL float bf2f(u16 h) { return __uint_as_float(((unsigned int)h) << 16); }

DEVINL f4 mfma_(b16x8 a, b16x8 b, f4 c) {
  return __builtin_amdgcn_mfma_f32_16x16x32_bf16(a, b, c, 0, 0, 0);
}
// bf16x3: (ah+al)*(bh+bl) ~= ah*bh + ah*bl + al*bh
DEVINL f4 mfma3(b16x8 ah, b16x8 al, b16x8 bh, b16x8 bl, f4 c) {
  c = mfma_(ah, bh, c);
  c = mfma_(ah, bl, c);
  c = mfma_(al, bh, c);
  return c;
}
DEVINL void gload16(const u16* g, u16* l) {
  __builtin_amdgcn_global_load_lds(
      (const __attribute__((address_space(1))) void*)g,
      (__attribute__((address_space(3))) void*)l, 16, 0, 0);
}

// ---- 16B-chunk XOR swizzle tile helpers (r5-proven, bank-conflict=0).
// BK=64 family (8 chunks/row):
DEVINL void stage_tile(const u16* __restrict__ gbase, int rstride,
                       u16* __restrict__ lds, int t) {      // 128x64, 256 thr
#pragma unroll
  for (int r = 0; r < 4; ++r) {
    int cp = r * 256 + t;
    int row = cp >> 3, j = cp & 7;
    int jj = j ^ (row & 7);
    gload16(&gbase[(size_t)row * rstride + jj * 8], &lds[cp * 8]);
  }
}
DEVINL void stageA256(const u16* __restrict__ gbase, int rstride,
                      u16* __restrict__ lds, int t) {       // 256x64, 512 thr
#pragma unroll
  for (int r = 0; r < 4; ++r) {
    int cp = r * 512 + t;                // 2048 chunks
    int row = cp >> 3, j = cp & 7;
    int jj = j ^ (row & 7);
    gload16(&gbase[(size_t)row * rstride + jj * 8], &lds[cp * 8]);
  }
}
DEVINL void stageB128(const u16* __restrict__ gbase, int rstride,
                      u16* __restrict__ lds, int t) {       // 128x64, 512 thr
#pragma unroll
  for (int r = 0; r < 2; ++r) {
    int cp = r * 512 + t;                // 1024 chunks
    int row = cp >> 3, j = cp & 7;
    int jj = j ^ (row & 7);
    gload16(&gbase[(size_t)row * rstride + jj * 8], &lds[cp * 8]);
  }
}
DEVINL b16x8 readfrag(const u16* __restrict__ lds, int row, int kk, int g) {
  int chunk = row * 8 + ((kk * 4 + g) ^ (row & 7));
  return *(const b16x8*)&lds[chunk * 8];
}
// BK=128 family (16 chunks/row), same involution logic over &15:
DEVINL void stageA256k128(const u16* __restrict__ gbase, int rstride,
                          u16* __restrict__ lds, int t) {   // 256x128, 512 thr
#pragma unroll
  for (int r = 0; r < 8; ++r) {
    int cp = r * 512 + t;                // 4096 chunks
    int row = cp >> 4, j = cp & 15;
    int jj = j ^ (row & 15);
    gload16(&gbase[(size_t)row * rstride + jj * 8], &lds[cp * 8]);
  }
}
DEVINL void stageB128k128(const u16* __restrict__ gbase, int rstride,
                          u16* __restrict__ lds, int t) {   // 128x128, 512 thr
#pragma unroll
  for (int r = 0; r < 4; ++r) {
    int cp = r * 512 + t;                // 2048 chunks
    int row = cp >> 4, j = cp & 15;
    int jj = j ^ (row & 15);
    gload16(&gbase[(size_t)row * rstride + jj * 8], &lds[cp * 8]);
  }
}
DEVINL b16x8 readfragk128(const u16* __restrict__ lds, int row, int kk, int g) {
  int chunk = row * 16 + ((kk * 4 + g) ^ (row & 15));
  return *(const b16x8*)&lds[chunk * 8];
}

// ---- r13 BK=64 core (unchanged; used by k_score / k_out).
template <int NT>
DEVINL void gemm_core(const u16* __restrict__ Ab, int sA,
                      const u16* __restrict__ Bb, int sB,
                      u16* __restrict__ ldsA, u16* __restrict__ ldsB,
                      int t, int wr, int wc, int ql, int g, f4 acc[4][4]) {
  b16x8 fa[4], fb[4];
  b16x8 ga[4], gb[4];
  stageA256(Ab, sA, ldsA, t);
  stageB128(Bb, sB, ldsB, t);
  stageA256(Ab + 64, sA, ldsA + 16384, t);
  stageB128(Bb + 64, sB, ldsB + 8192, t);
  asm volatile("s_waitcnt vmcnt(6)" ::: "memory");
  __builtin_amdgcn_s_barrier();
  asm volatile("" ::: "memory");
  u16 *cA = ldsA, *cB = ldsB, *nA = ldsA + 16384, *nB = ldsB + 8192;
#pragma unroll
  for (int i = 0; i < 4; ++i) {
    fa[i] = readfrag(cA, wr * 64 + i * 16 + ql, 0, g);
    fb[i] = readfrag(cB, wc * 64 + i * 16 + ql, 0, g);
  }
  for (int j = 0; j < NT; ++j) {
#pragma unroll
    for (int i = 0; i < 4; ++i) {
      ga[i] = readfrag(cA, wr * 64 + i * 16 + ql, 1, g);
      gb[i] = readfrag(cB, wc * 64 + i * 16 + ql, 1, g);
    }
    __builtin_amdgcn_s_setprio(1);
#pragma unroll
    for (int rt = 0; rt < 4; ++rt)
#pragma unroll
      for (int ct = 0; ct < 4; ++ct)
        acc[rt][ct] = mfma_(fa[rt], fb[ct], acc[rt][ct]);
    __builtin_amdgcn_s_setprio(0);
    asm volatile("s_waitcnt vmcnt(0)" ::: "memory");
    __builtin_amdgcn_s_barrier();
    asm volatile("" ::: "memory");
    if (j + 1 < NT) {
#pragma unroll
      for (int i = 0; i < 4; ++i) {
        fa[i] = readfrag(nA, wr * 64 + i * 16 + ql, 0, g);
        fb[i] = readfrag(nB, wc * 64 + i * 16 + ql, 0, g);
      }
    }
    if (j + 2 < NT) {
      stageA256(Ab + (j + 2) * 64, sA, cA, t);
      stageB128(Bb + (j + 2) * 64, sB, cB, t);
    }
    __builtin_amdgcn_s_setprio(1);
#pragma unroll
    for (int rt = 0; rt < 4; ++rt)
#pragma unroll
      for (int ct = 0; ct < 4; ++ct)
        acc[rt][ct] = mfma_(ga[rt], gb[ct], acc[rt][ct]);
    __builtin_amdgcn_s_setprio(0);
    u16* tmp = cA; cA = nA; nA = tmp;
    tmp = cB; cB = nB; nB = tmp;
  }
}

// ---------------------------------------------------------------------------
// K0: merged prep (unchanged).
__global__ __launch_bounds__(256) void k_prep(
    const float* __restrict__ x, const float* __restrict__ Wk,
    const float* __restrict__ Wq, const float* __restrict__ Wv,
    const float* __restrict__ Wa, const float* __restrict__ Wb,
    u16* __restrict__ xh, u16* __restrict__ wh,
    u16* __restrict__ waT_h, u16* __restrict__ waT_l,
    u16* __restrict__ wqT_h, u16* __restrict__ wqT_l,
    u16* __restrict__ wb_h, u16* __restrict__ wb_l,
    u16* __restrict__ wvT_h, u16* __restrict__ wvT_l,
    float* __restrict__ l) {
  const int bid = blockIdx.x, t = threadIdx.x;
  if (bid < 8192) {
    int i = bid * 256 + t;
    float4 v = ((const float4*)x)[i];
    ushort4 h;
    h.x = f2bf(v.x); h.y = f2bf(v.y); h.z = f2bf(v.z); h.w = f2bf(v.w);
    ((ushort4*)xh)[i] = h;
    return;
  }
  if (bid < 8704) {
    int i = (bid - 8192) * 256 + t;
    float4 v = ((const float4*)Wk)[i];
    ushort4 h;
    h.x = f2bf(v.x); h.y = f2bf(v.y); h.z = f2bf(v.z); h.w = f2bf(v.w);
    ((ushort4*)wh)[i] = h;
    return;
  }
  if (bid < 8960) {
    int i = (bid - 8704) * 256 + t;
    float4 v = ((const float4*)Wb)[i];
    ushort4 h, lo;
    h.x = f2bf(v.x); lo.x = f2bf(v.x - bf2f(h.x));
    h.y = f2bf(v.y); lo.y = f2bf(v.y - bf2f(h.y));
    h.z = f2bf(v.z); lo.z = f2bf(v.z - bf2f(h.z));
    h.w = f2bf(v.w); lo.w = f2bf(v.w - bf2f(h.w));
    ((ushort4*)wb_h)[i] = h;
    ((ushort4*)wb_l)[i] = lo;
    return;
  }
  if (bid >= 9280) {
    int i = (bid - 9280) * 256 + t;
    float4 z = {0.f, 0.f, 0.f, 0.f};
    ((float4*)l)[i] = z;
    return;
  }
  __shared__ float ftile[64][68];
  const int tb = bid - 8960;
  const float* src;
  u16 *dh, *dl;
  int S, m0, c0;
  if (tb < 64) {
    src = Wa; dh = waT_h; dl = waT_l; S = 512;
    m0 = (tb >> 3) * 64; c0 = (tb & 7) * 64;
  } else if (tb < 192) {
    int q = tb - 64;
    src = Wq; dh = wqT_h; dl = wqT_l; S = 1024;
    m0 = (q >> 4) * 64; c0 = (q & 15) * 64;
  } else {
    int q = tb - 192;
    src = Wv; dh = wvT_h; dl = wvT_l; S = 1024;
    m0 = (q >> 4) * 64; c0 = (q & 15) * 64;
  }
  {
    int i = t >> 4, j4 = (t & 15) * 4;
#pragma unroll
    for (int ii = 0; ii < 4; ++ii) {
      int row = i + ii * 16;
      float4 v = *(const float4*)&src[(size_t)(m0 + row) * S + c0 + j4];
      ftile[row][j4] = v.x; ftile[row][j4 + 1] = v.y;
      ftile[row][j4 + 2] = v.z; ftile[row][j4 + 3] = v.w;
    }
  }
  __syncthreads();
  {
    int oc = t >> 2, mc = (t & 3) * 16;
#pragma unroll
    for (int j = 0; j < 4; ++j) {
      int m = mc + j * 4;
      float v0 = ftile[m][oc], v1 = ftile[m + 1][oc];
      float v2 = ftile[m + 2][oc], v3 = ftile[m + 3][oc];
      ushort4 h, lo;
      h.x = f2bf(v0); lo.x = f2bf(v0 - bf2f(h.x));
      h.y = f2bf(v1); lo.y = f2bf(v1 - bf2f(h.y));
      h.z = f2bf(v2); lo.z = f2bf(v2 - bf2f(h.z));
      h.w = f2bf(v3); lo.w = f2bf(v3 - bf2f(h.w));
      size_t o = (size_t)(c0 + oc) * 512 + m0 + m;
      *(ushort4*)&dh[o] = h;
      *(ushort4*)&dl[o] = lo;
    }
  }
}

// ---------------------------------------------------------------------------
// K1: fold GEMMs, bf16x3 (unchanged).
__global__ __launch_bounds__(256, 2) void k_fold_mfma(
    const u16* __restrict__ waT_h, const u16* __restrict__ waT_l,
    const u16* __restrict__ wqT_h, const u16* __restrict__ wqT_l,
    const u16* __restrict__ wb_h, const u16* __restrict__ wb_l,
    const u16* __restrict__ wvT_h, const u16* __restrict__ wvT_l,
    u16* __restrict__ wh) {
  __shared__ u16 lah[8192], lal[8192], lbh[8192], lbl[8192];
  const int blk = blockIdx.x;
  const int which = blk >> 5;
  const int idx = blk & 31;
  const int r0 = (idx >> 3) * 128, c0 = (idx & 7) * 128;
  const u16* Ah = which ? wb_h : waT_h;
  const u16* Al = which ? wb_l : waT_l;
  const u16* Bh = which ? wvT_h : wqT_h;
  const u16* Bl = which ? wvT_l : wqT_l;
  const int obase = which ? 1024 : 512;
  const int t = threadIdx.x, lane = t & 63, w = t >> 6;
  const int wr = w >> 1, wc = w & 1, ql = lane & 15, g = lane >> 4;
  const f4 fzero = {0.f, 0.f, 0.f, 0.f};
  f4 acc[4][4];
#pragma unroll
  for (int i = 0; i < 4; ++i)
#pragma unroll
    for (int j = 0; j < 4; ++j) acc[i][j] = fzero;

  for (int ks = 0; ks < 8; ++ks) {
    __syncthreads();
    stage_tile(&Ah[(size_t)r0 * 512 + ks * 64], 512, lah, t);
    stage_tile(&Al[(size_t)r0 * 512 + ks * 64], 512, lal, t);
    stage_tile(&Bh[(size_t)c0 * 512 + ks * 64], 512, lbh, t);
    stage_tile(&Bl[(size_t)c0 * 512 + ks * 64], 512, lbl, t);
    __syncthreads();
#pragma unroll
    for (int kk = 0; kk < 2; ++kk) {
      b16x8 ah[4], al[4], bh[4], bl[4];
#pragma unroll
      for (int rt = 0; rt < 4; ++rt) {
        ah[rt] = readfrag(lah, wr * 64 + rt * 16 + ql, kk, g);
        al[rt] = readfrag(lal, wr * 64 + rt * 16 + ql, kk, g);
      }
#pragma unroll
      for (int ct = 0; ct < 4; ++ct) {
        bh[ct] = readfrag(lbh, wc * 64 + ct * 16 + ql, kk, g);
        bl[ct] = readfrag(lbl, wc * 64 + ct * 16 + ql, kk, g);
      }
#pragma unroll
      for (int rt = 0; rt < 4; ++rt)
#pragma unroll
        for (int ct = 0; ct < 4; ++ct)
          acc[rt][ct] = mfma3(ah[rt], al[rt], bh[ct], bl[ct], acc[rt][ct]);
    }
  }
#pragma unroll
  for (int rt = 0; rt < 4; ++rt) {
#pragma unroll
    for (int ct = 0; ct < 4; ++ct) {
      f4 v = acc[rt][ct];
      int col = c0 + wc * 64 + ct * 16 + ql;
      int rowb = r0 + wr * 64 + rt * 16 + g * 4;
#pragma unroll
      for (int r = 0; r < 4; ++r)
        wh[(size_t)(obase + rowb + r) * 1024 + col] = f2bf(v[r]);
    }
  }
}

// ---------------------------------------------------------------------------
// K2: projection GEMM, 256x128 tiles, BK=128 (8 K-tiles). Grid 384:
//  bid<256: KP. A=wh f-rows (Mt 0..3), B=xh s-rows (Nt 0..63) -> C[f][s].
//  bid>=256: U. A=xh s-rows (Mt 0..31), B=wh U-rows (Nt 0..3) -> C[s][d].
// A single-buffered (64KB); B double-buffered (2x32KB). 2 barriers/tile.
__global__ __launch_bounds__(512, 1) void k_proj(
    const u16* __restrict__ xh, const u16* __restrict__ wh,
    u16* __restrict__ kh, u16* __restrict__ ph, u16* __restrict__ ut) {
  __shared__ u16 lA[32768];        // 256x128 bf16 = 64 KB
  __shared__ u16 lB[2][16384];     // 2 x (128x128 bf16 = 32 KB)
  const int bid = blockIdx.x;
  const int t = threadIdx.x, lane = t & 63, w = t >> 6;
  const int wr = w >> 1, wc = w & 1, ql = lane & 15, g = lane >> 4;
  const f4 fzero = {0.f, 0.f, 0.f, 0.f};
  f4 acc[4][4];
#pragma unroll
  for (int i = 0; i < 4; ++i)
#pragma unroll
    for (int j = 0; j < 4; ++j) acc[i][j] = fzero;

  const bool kp = bid < 256;
  int Mt, Nt;
  const u16 *Ab, *Bb;
  if (kp) {
    Mt = bid >> 6;                         // 0..3
    Nt = bid & 63;                         // 0..63
    Ab = wh + (size_t)(Mt * 256) * 1024;
    Bb = xh + (size_t)(Nt * 128) * 1024;
  } else {
    int b2 = bid - 256;
    Mt = b2 >> 2;                          // 0..31
    Nt = b2 & 3;                           // 0..3
    Ab = xh + (size_t)(Mt * 256) * 1024;
    Bb = wh + (size_t)(1024 + Nt * 128) * 1024;
  }
  constexpr int NT = 8;                    // K = 1024 / 128

  // prologue: A(0), B(0), B(1) — B(1) issued LAST so vmcnt(4) lets it fly.
  stageA256k128(Ab, 1024, lA, t);
  stageB128k128(Bb, 1024, lB[0], t);
  stageB128k128(Bb + 128, 1024, lB[1], t);
  asm volatile("s_waitcnt vmcnt(4)" ::: "memory");
  __builtin_amdgcn_s_barrier();
  asm volatile("" ::: "memory");

  for (int j = 0; j < NT; ++j) {
    const u16* lbc = lB[j & 1];
    // ---- compute tile j: 4 kk-steps of K=32 (compiler pipelines lgkm waits)
#pragma unroll
    for (int kk = 0; kk < 4; ++kk) {
      b16x8 af[4], bf[4];
#pragma unroll
      for (int i = 0; i < 4; ++i) {
        af[i] = readfragk128(lA, wr * 64 + i * 16 + ql, kk, g);
        bf[i] = readfragk128(lbc, wc * 64 + i * 16 + ql, kk, g);
      }
      __builtin_amdgcn_s_setprio(1);
#pragma unroll
      for (int rt = 0; rt < 4; ++rt)
#pragma unroll
        for (int ct = 0; ct < 4; ++ct)
          acc[rt][ct] = mfma_(af[rt], bf[ct], acc[rt][ct]);
      __builtin_amdgcn_s_setprio(0);
    }
    if (j + 1 == NT) break;
    __builtin_amdgcn_s_barrier();          // all waves done with A(j), B(j)
    asm volatile("" ::: "memory");
    // ---- stage A(j+1) (8 loads), then B(j+2) (4 loads, newest)
    stageA256k128(Ab + (j + 1) * 128, 1024, lA, t);
    if (j + 2 < NT) {
      stageB128k128(Bb + (j + 2) * 128, 1024, lB[j & 1], t);
      asm volatile("s_waitcnt vmcnt(4)" ::: "memory");  // A(j+1)+B(j+1) done
    } else {
      asm volatile("s_waitcnt vmcnt(0)" ::: "memory");
    }
    __builtin_amdgcn_s_barrier();
    asm volatile("" ::: "memory");
  }

  if (kp) {
    // C[f][s]: f4 over 4 consecutive f at fixed s
#pragma unroll
    for (int rt = 0; rt < 4; ++rt) {
#pragma unroll
      for (int ct = 0; ct < 4; ++ct) {
        f4 v = acc[rt][ct];
        int f = Mt * 256 + wr * 64 + rt * 16 + g * 4;
        int s = Nt * 128 + wc * 64 + ct * 16 + ql;
        ushort4 hh;
        hh.x = f2bf(v[0]); hh.y = f2bf(v[1]); hh.z = f2bf(v[2]); hh.w = f2bf(v[3]);
        if (f < 512) *(ushort4*)&kh[(size_t)s * 512 + f] = hh;
        else         *(ushort4*)&ph[(size_t)s * 512 + (f - 512)] = hh;
      }
    }
  } else {
    // C[s][d]: f4 over 4 consecutive s -> ut[b][d][k] ushort4 along k
#pragma unroll
    for (int rt = 0; rt < 4; ++rt) {
#pragma unroll
      for (int ct = 0; ct < 4; ++ct) {
        f4 v = acc[rt][ct];
        int s = Mt * 256 + wr * 64 + rt * 16 + g * 4;
        int d = Nt * 128 + wc * 64 + ct * 16 + ql;
        int bb = s >> 11, k0 = s & 2047;
        ushort4 hh;
        hh.x = f2bf(v[0]); hh.y = f2bf(v[1]); hh.z = f2bf(v[2]); hh.w = f2bf(v[3]);
        *(ushort4*)&ut[((size_t)bb * 512 + d) * 2048 + k0] = hh;
      }
    }
  }
}

// ---------------------------------------------------------------------------
// K3: score GEMM (unchanged r13). Grid 512.
__global__ __launch_bounds__(512, 2) void k_score(
    const u16* __restrict__ ph, const u16* __restrict__ kh,
    u16* __restrict__ probs, float* __restrict__ l) {
  constexpr float INVT = 0.04419417382415922f;  // 1/sqrt(512)
  __shared__ u16 lA[2 * 16384], lB[2 * 8192];
  const int bid = blockIdx.x;
  const int b = bid >> 7, rem = bid & 127;
  const int Mt = rem >> 4, Nt = rem & 15;
  const int k0b = Mt * 256, q0b = Nt * 128;
  const int t = threadIdx.x, lane = t & 63, w = t >> 6;
  const int wr = w >> 1, wc = w & 1, ql = lane & 15, g = lane >> 4;
  const f4 fzero = {0.f, 0.f, 0.f, 0.f};
  f4 acc[4][4];
#pragma unroll
  for (int i = 0; i < 4; ++i)
#pragma unroll
    for (int j = 0; j < 4; ++j) acc[i][j] = fzero;

  const u16* Ab = &kh[((size_t)b * 2048 + k0b) * 512];
  const u16* Bb = &ph[((size_t)b * 2048 + q0b) * 512];
  gemm_core<8>(Ab, 512, Bb, 512, lA, lB, t, wr, wc, ql, g, acc);

  float lq[4] = {0.f, 0.f, 0.f, 0.f};
#pragma unroll
  for (int rt = 0; rt < 4; ++rt) {
    int kr = k0b + wr * 64 + rt * 16 + g * 4;
#pragma unroll
    for (int ct = 0; ct < 4; ++ct) {
      int q = q0b + wc * 64 + ct * 16 + ql;
      f4 a = acc[rt][ct];
      float p0 = __expf(a[0] * INVT), p1 = __expf(a[1] * INVT);
      float p2 = __expf(a[2] * INVT), p3 = __expf(a[3] * INVT);
      ushort4 hh;
      hh.x = f2bf(p0); hh.y = f2bf(p1); hh.z = f2bf(p2); hh.w = f2bf(p3);
      *(ushort4*)&probs[((size_t)b * 2048 + q) * 2048 + kr] = hh;
      lq[ct] += (p0 + p1) + (p2 + p3);
    }
  }
#pragma unroll
  for (int ct = 0; ct < 4; ++ct) {
    float s = lq[ct];
    s += __shfl_xor(s, 16);
    s += __shfl_xor(s, 32);
    if (lane < 16) atomicAdd(&l[b * 2048 + q0b + wc * 64 + ct * 16 + lane], s);
  }
}

// ---------------------------------------------------------------------------
// K4: output GEMM (unchanged r13). Grid 128.
__global__ __launch_bounds__(512, 2) void k_out(
    const u16* __restrict__ ut, const u16* __restrict__ probs,
    const float* __restrict__ l, float* __restrict__ out) {
  __shared__ u16 lA[2 * 16384], lB[2 * 8192];
  const int bid = blockIdx.x;
  const int b = bid >> 5, rem = bid & 31;
  const int Mt = rem >> 4, Nt = rem & 15;
  const int d0 = Mt * 256, q0 = Nt * 128;
  const int t = threadIdx.x, lane = t & 63, w = t >> 6;
  const int wr = w >> 1, wc = w & 1, ql = lane & 15, g = lane >> 4;
  const f4 fzero = {0.f, 0.f, 0.f, 0.f};
  f4 acc[4][4];
#pragma unroll
  for (int i = 0; i < 4; ++i)
#pragma unroll
    for (int j = 0; j < 4; ++j) acc[i][j] = fzero;

  const u16* Ab = &ut[((size_t)b * 512 + d0) * 2048];
  const u16* Bb = &probs[((size_t)b * 2048 + q0) * 2048];
  gemm_core<32>(Ab, 2048, Bb, 2048, lA, lB, t, wr, wc, ql, g, acc);

#pragma unroll
  for (int ct = 0; ct < 4; ++ct) {
    int q = q0 + wc * 64 + ct * 16 + ql;
    float inv = 1.0f / l[b * 2048 + q];
    size_t orow = ((size_t)b * 2048 + q) * 512;
#pragma unroll
    for (int rt = 0; rt < 4; ++rt) {
      int d = d0 + wr * 64 + rt * 16 + g * 4;
      f4 v = acc[rt][ct] * inv;
      *(f4*)&out[orow + d] = v;
    }
  }
}

// ---------------------------------------------------------------------------
extern "C" void kernel_launch(void* const* d_in, const int* in_sizes, int n_in,
                              void* d_out, int out_size, void* d_ws, size_t ws_size,
                              hipStream_t stream) {
  const float* x = (const float*)d_in[0];
  const float* Wk = (const float*)d_in[1];
  const float* Wq = (const float*)d_in[2];
  const float* Wv = (const float*)d_in[3];
  const float* Wa = (const float*)d_in[4];
  const float* Wb = (const float*)d_in[5];
  float* out = (float*)d_out;

  char* ws = (char*)d_ws;
  size_t off = 0;
  auto alloc = [&](size_t bytes) -> void* {
    void* p = ws + off;
    off += (bytes + 255) & ~(size_t)255;
    return p;
  };
  u16* wh = (u16*)alloc((size_t)1536 * 1024 * 2);
  u16* xh = (u16*)alloc((size_t)8192 * 1024 * 2);
  u16* kh = (u16*)alloc((size_t)8192 * 512 * 2);
  u16* ph = (u16*)alloc((size_t)8192 * 512 * 2);
  u16* ut = (u16*)alloc((size_t)8192 * 512 * 2);
  u16* probs = (u16*)alloc((size_t)4 * 2048 * 2048 * 2);
  float* l = (float*)alloc(8192 * 4);
  u16* waT_h = (u16*)alloc((size_t)512 * 512 * 2);
  u16* waT_l = (u16*)alloc((size_t)512 * 512 * 2);
  u16* wqT_h = (u16*)alloc((size_t)1024 * 512 * 2);
  u16* wqT_l = (u16*)alloc((size_t)1024 * 512 * 2);
  u16* wb_h = (u16*)alloc((size_t)512 * 512 * 2);
  u16* wb_l = (u16*)alloc((size_t)512 * 512 * 2);
  u16* wvT_h = (u16*)alloc((size_t)1024 * 512 * 2);
  u16* wvT_l = (u16*)alloc((size_t)1024 * 512 * 2);
  (void)ws_size; (void)in_sizes; (void)n_in; (void)out_size;

  hipLaunchKernelGGL(k_prep, dim3(9288), dim3(256), 0, stream,
                     x, Wk, Wq, Wv, Wa, Wb, xh, wh,
                     waT_h, waT_l, wqT_h, wqT_l, wb_h, wb_l, wvT_h, wvT_l, l);
  hipLaunchKernelGGL(k_fold_mfma, dim3(64), dim3(256), 0, stream,
                     waT_h, waT_l, wqT_h, wqT_l, wb_h, wb_l, wvT_h, wvT_l, wh);
  hipLaunchKernelGGL(k_proj, dim3(384), dim3(512), 0, stream, xh, wh, kh, ph, ut);
  hipLaunchKernelGGL(k_score, dim3(512), dim3(512), 0, stream, ph, kh, probs, l);
  hipLaunchKernelGGL(k_out, dim3(128), dim3(512), 0, stream, ut, probs, l, out);
}

// Round 15
// 128.594 us; speedup vs baseline: 1.1192x; 1.1192x over previous
//
#include <hip/hip_runtime.h>

// SelfAttention_33852932227207 — MI355X, round 15.
// e = x^T (Wq^T Wa Wk) x / sqrt(512);  out = softmax(e) @ (x (Wb Wv)^T).
// r7-r14: five k_proj inner-loop structures all land 43-51 µs (~586 TF,
// no pipe saturated) -> inner schedule declared at plain-HIP ceiling; frozen.
// r15 targets the REAL second cost: k_out ran 128 blocks @1/CU = half the
// chip idle (~40 µs hidden). New k_out: 128x128 tiles, 256 blocks (full
// coverage), 4-wave blocks, per-wave 64x64, same reads-ahead core with
// 128-row A (gemm_core128), LDS 64KB. K-accumulation order per output
// unchanged -> bit-identical (absmax 2.441e-4). Everything else = r13.

typedef __attribute__((ext_vector_type(8))) short b16x8;
typedef __attribute__((ext_vector_type(4))) float f4;
typedef unsigned short u16;

#define DEVINL __device__ __forceinline__

DEVINL u16 f2bf(float f) {               // fp32 -> bf16 RNE
  unsigned int u = __float_as_uint(f);
  u = u + 0x7FFFu + ((u >> 16) & 1u);
  return (u16)(u >> 16);
}
DEVINL float bf2f(u16 h) { return __uint_as_float(((unsigned int)h) << 16); }

DEVINL f4 mfma_(b16x8 a, b16x8 b, f4 c) {
  return __builtin_amdgcn_mfma_f32_16x16x32_bf16(a, b, c, 0, 0, 0);
}
// bf16x3: (ah+al)*(bh+bl) ~= ah*bh + ah*bl + al*bh
DEVINL f4 mfma3(b16x8 ah, b16x8 al, b16x8 bh, b16x8 bl, f4 c) {
  c = mfma_(ah, bh, c);
  c = mfma_(ah, bl, c);
  c = mfma_(al, bh, c);
  return c;
}
DEVINL void gload16(const u16* g, u16* l) {
  __builtin_amdgcn_global_load_lds(
      (const __attribute__((address_space(1))) void*)g,
      (__attribute__((address_space(3))) void*)l, 16, 0, 0);
}

// ---- 16B-chunk XOR swizzle tile helpers (r5-proven, bank-conflict=0).
DEVINL void stage_tile(const u16* __restrict__ gbase, int rstride,
                       u16* __restrict__ lds, int t) {      // 128x64, 256 thr
#pragma unroll
  for (int r = 0; r < 4; ++r) {
    int cp = r * 256 + t;
    int row = cp >> 3, j = cp & 7;
    int jj = j ^ (row & 7);
    gload16(&gbase[(size_t)row * rstride + jj * 8], &lds[cp * 8]);
  }
}
DEVINL void stageA256(const u16* __restrict__ gbase, int rstride,
                      u16* __restrict__ lds, int t) {       // 256x64, 512 thr
#pragma unroll
  for (int r = 0; r < 4; ++r) {
    int cp = r * 512 + t;                // 2048 chunks
    int row = cp >> 3, j = cp & 7;
    int jj = j ^ (row & 7);
    gload16(&gbase[(size_t)row * rstride + jj * 8], &lds[cp * 8]);
  }
}
DEVINL void stageB128(const u16* __restrict__ gbase, int rstride,
                      u16* __restrict__ lds, int t) {       // 128x64, 512 thr
#pragma unroll
  for (int r = 0; r < 2; ++r) {
    int cp = r * 512 + t;                // 1024 chunks
    int row = cp >> 3, j = cp & 7;
    int jj = j ^ (row & 7);
    gload16(&gbase[(size_t)row * rstride + jj * 8], &lds[cp * 8]);
  }
}
DEVINL b16x8 readfrag(const u16* __restrict__ lds, int row, int kk, int g) {
  int chunk = row * 8 + ((kk * 4 + g) ^ (row & 7));
  return *(const b16x8*)&lds[chunk * 8];
}

// ---- r13 core: 256x128 BK=64 8-wave, reads-one-half-ahead (k_proj/k_score).
template <int NT>
DEVINL void gemm_core(const u16* __restrict__ Ab, int sA,
                      const u16* __restrict__ Bb, int sB,
                      u16* __restrict__ ldsA, u16* __restrict__ ldsB,
                      int t, int wr, int wc, int ql, int g, f4 acc[4][4]) {
  b16x8 fa[4], fb[4];
  b16x8 ga[4], gb[4];
  stageA256(Ab, sA, ldsA, t);
  stageB128(Bb, sB, ldsB, t);
  stageA256(Ab + 64, sA, ldsA + 16384, t);
  stageB128(Bb + 64, sB, ldsB + 8192, t);
  asm volatile("s_waitcnt vmcnt(6)" ::: "memory");
  __builtin_amdgcn_s_barrier();
  asm volatile("" ::: "memory");
  u16 *cA = ldsA, *cB = ldsB, *nA = ldsA + 16384, *nB = ldsB + 8192;
#pragma unroll
  for (int i = 0; i < 4; ++i) {
    fa[i] = readfrag(cA, wr * 64 + i * 16 + ql, 0, g);
    fb[i] = readfrag(cB, wc * 64 + i * 16 + ql, 0, g);
  }
  for (int j = 0; j < NT; ++j) {
#pragma unroll
    for (int i = 0; i < 4; ++i) {
      ga[i] = readfrag(cA, wr * 64 + i * 16 + ql, 1, g);
      gb[i] = readfrag(cB, wc * 64 + i * 16 + ql, 1, g);
    }
    __builtin_amdgcn_s_setprio(1);
#pragma unroll
    for (int rt = 0; rt < 4; ++rt)
#pragma unroll
      for (int ct = 0; ct < 4; ++ct)
        acc[rt][ct] = mfma_(fa[rt], fb[ct], acc[rt][ct]);
    __builtin_amdgcn_s_setprio(0);
    asm volatile("s_waitcnt vmcnt(0)" ::: "memory");
    __builtin_amdgcn_s_barrier();
    asm volatile("" ::: "memory");
    if (j + 1 < NT) {
#pragma unroll
      for (int i = 0; i < 4; ++i) {
        fa[i] = readfrag(nA, wr * 64 + i * 16 + ql, 0, g);
        fb[i] = readfrag(nB, wc * 64 + i * 16 + ql, 0, g);
      }
    }
    if (j + 2 < NT) {
      stageA256(Ab + (j + 2) * 64, sA, cA, t);
      stageB128(Bb + (j + 2) * 64, sB, cB, t);
    }
    __builtin_amdgcn_s_setprio(1);
#pragma unroll
    for (int rt = 0; rt < 4; ++rt)
#pragma unroll
      for (int ct = 0; ct < 4; ++ct)
        acc[rt][ct] = mfma_(ga[rt], gb[ct], acc[rt][ct]);
    __builtin_amdgcn_s_setprio(0);
    u16* tmp = cA; cA = nA; nA = tmp;
    tmp = cB; cB = nB; nB = tmp;
  }
}

// ---- r15 core: 128x128 BK=64 4-wave (256 thr), same discipline (k_out).
// Buffer stride 8192 u16 = 16 KB per operand tile.
template <int NT>
DEVINL void gemm_core128(const u16* __restrict__ Ab, int sA,
                         const u16* __restrict__ Bb, int sB,
                         u16* __restrict__ ldsA, u16* __restrict__ ldsB,
                         int t, int wr, int wc, int ql, int g, f4 acc[4][4]) {
  b16x8 fa[4], fb[4];
  b16x8 ga[4], gb[4];
  stage_tile(Ab, sA, ldsA, t);
  stage_tile(Bb, sB, ldsB, t);
  stage_tile(Ab + 64, sA, ldsA + 8192, t);
  stage_tile(Bb + 64, sB, ldsB + 8192, t);
  asm volatile("s_waitcnt vmcnt(8)" ::: "memory");   // tile0 (8 newest = tile1)
  __builtin_amdgcn_s_barrier();
  asm volatile("" ::: "memory");
  u16 *cA = ldsA, *cB = ldsB, *nA = ldsA + 8192, *nB = ldsB + 8192;
#pragma unroll
  for (int i = 0; i < 4; ++i) {
    fa[i] = readfrag(cA, wr * 64 + i * 16 + ql, 0, g);
    fb[i] = readfrag(cB, wc * 64 + i * 16 + ql, 0, g);
  }
  for (int j = 0; j < NT; ++j) {
#pragma unroll
    for (int i = 0; i < 4; ++i) {
      ga[i] = readfrag(cA, wr * 64 + i * 16 + ql, 1, g);
      gb[i] = readfrag(cB, wc * 64 + i * 16 + ql, 1, g);
    }
    __builtin_amdgcn_s_setprio(1);
#pragma unroll
    for (int rt = 0; rt < 4; ++rt)
#pragma unroll
      for (int ct = 0; ct < 4; ++ct)
        acc[rt][ct] = mfma_(fa[rt], fb[ct], acc[rt][ct]);
    __builtin_amdgcn_s_setprio(0);
    asm volatile("s_waitcnt vmcnt(0)" ::: "memory");
    __builtin_amdgcn_s_barrier();
    asm volatile("" ::: "memory");
    if (j + 1 < NT) {
#pragma unroll
      for (int i = 0; i < 4; ++i) {
        fa[i] = readfrag(nA, wr * 64 + i * 16 + ql, 0, g);
        fb[i] = readfrag(nB, wc * 64 + i * 16 + ql, 0, g);
      }
    }
    if (j + 2 < NT) {
      stage_tile(Ab + (j + 2) * 64, sA, cA, t);
      stage_tile(Bb + (j + 2) * 64, sB, cB, t);
    }
    __builtin_amdgcn_s_setprio(1);
#pragma unroll
    for (int rt = 0; rt < 4; ++rt)
#pragma unroll
      for (int ct = 0; ct < 4; ++ct)
        acc[rt][ct] = mfma_(ga[rt], gb[ct], acc[rt][ct]);
    __builtin_amdgcn_s_setprio(0);
    u16* tmp = cA; cA = nA; nA = tmp;
    tmp = cB; cB = nB; nB = tmp;
  }
}

// ---------------------------------------------------------------------------
// K0: merged prep (unchanged).
__global__ __launch_bounds__(256) void k_prep(
    const float* __restrict__ x, const float* __restrict__ Wk,
    const float* __restrict__ Wq, const float* __restrict__ Wv,
    const float* __restrict__ Wa, const float* __restrict__ Wb,
    u16* __restrict__ xh, u16* __restrict__ wh,
    u16* __restrict__ waT_h, u16* __restrict__ waT_l,
    u16* __restrict__ wqT_h, u16* __restrict__ wqT_l,
    u16* __restrict__ wb_h, u16* __restrict__ wb_l,
    u16* __restrict__ wvT_h, u16* __restrict__ wvT_l,
    float* __restrict__ l) {
  const int bid = blockIdx.x, t = threadIdx.x;
  if (bid < 8192) {
    int i = bid * 256 + t;
    float4 v = ((const float4*)x)[i];
    ushort4 h;
    h.x = f2bf(v.x); h.y = f2bf(v.y); h.z = f2bf(v.z); h.w = f2bf(v.w);
    ((ushort4*)xh)[i] = h;
    return;
  }
  if (bid < 8704) {
    int i = (bid - 8192) * 256 + t;
    float4 v = ((const float4*)Wk)[i];
    ushort4 h;
    h.x = f2bf(v.x); h.y = f2bf(v.y); h.z = f2bf(v.z); h.w = f2bf(v.w);
    ((ushort4*)wh)[i] = h;
    return;
  }
  if (bid < 8960) {
    int i = (bid - 8704) * 256 + t;
    float4 v = ((const float4*)Wb)[i];
    ushort4 h, lo;
    h.x = f2bf(v.x); lo.x = f2bf(v.x - bf2f(h.x));
    h.y = f2bf(v.y); lo.y = f2bf(v.y - bf2f(h.y));
    h.z = f2bf(v.z); lo.z = f2bf(v.z - bf2f(h.z));
    h.w = f2bf(v.w); lo.w = f2bf(v.w - bf2f(h.w));
    ((ushort4*)wb_h)[i] = h;
    ((ushort4*)wb_l)[i] = lo;
    return;
  }
  if (bid >= 9280) {
    int i = (bid - 9280) * 256 + t;
    float4 z = {0.f, 0.f, 0.f, 0.f};
    ((float4*)l)[i] = z;
    return;
  }
  __shared__ float ftile[64][68];
  const int tb = bid - 8960;
  const float* src;
  u16 *dh, *dl;
  int S, m0, c0;
  if (tb < 64) {
    src = Wa; dh = waT_h; dl = waT_l; S = 512;
    m0 = (tb >> 3) * 64; c0 = (tb & 7) * 64;
  } else if (tb < 192) {
    int q = tb - 64;
    src = Wq; dh = wqT_h; dl = wqT_l; S = 1024;
    m0 = (q >> 4) * 64; c0 = (q & 15) * 64;
  } else {
    int q = tb - 192;
    src = Wv; dh = wvT_h; dl = wvT_l; S = 1024;
    m0 = (q >> 4) * 64; c0 = (q & 15) * 64;
  }
  {
    int i = t >> 4, j4 = (t & 15) * 4;
#pragma unroll
    for (int ii = 0; ii < 4; ++ii) {
      int row = i + ii * 16;
      float4 v = *(const float4*)&src[(size_t)(m0 + row) * S + c0 + j4];
      ftile[row][j4] = v.x; ftile[row][j4 + 1] = v.y;
      ftile[row][j4 + 2] = v.z; ftile[row][j4 + 3] = v.w;
    }
  }
  __syncthreads();
  {
    int oc = t >> 2, mc = (t & 3) * 16;
#pragma unroll
    for (int j = 0; j < 4; ++j) {
      int m = mc + j * 4;
      float v0 = ftile[m][oc], v1 = ftile[m + 1][oc];
      float v2 = ftile[m + 2][oc], v3 = ftile[m + 3][oc];
      ushort4 h, lo;
      h.x = f2bf(v0); lo.x = f2bf(v0 - bf2f(h.x));
      h.y = f2bf(v1); lo.y = f2bf(v1 - bf2f(h.y));
      h.z = f2bf(v2); lo.z = f2bf(v2 - bf2f(h.z));
      h.w = f2bf(v3); lo.w = f2bf(v3 - bf2f(h.w));
      size_t o = (size_t)(c0 + oc) * 512 + m0 + m;
      *(ushort4*)&dh[o] = h;
      *(ushort4*)&dl[o] = lo;
    }
  }
}

// ---------------------------------------------------------------------------
// K1: fold GEMMs, bf16x3 (unchanged).
__global__ __launch_bounds__(256, 2) void k_fold_mfma(
    const u16* __restrict__ waT_h, const u16* __restrict__ waT_l,
    const u16* __restrict__ wqT_h, const u16* __restrict__ wqT_l,
    const u16* __restrict__ wb_h, const u16* __restrict__ wb_l,
    const u16* __restrict__ wvT_h, const u16* __restrict__ wvT_l,
    u16* __restrict__ wh) {
  __shared__ u16 lah[8192], lal[8192], lbh[8192], lbl[8192];
  const int blk = blockIdx.x;
  const int which = blk >> 5;
  const int idx = blk & 31;
  const int r0 = (idx >> 3) * 128, c0 = (idx & 7) * 128;
  const u16* Ah = which ? wb_h : waT_h;
  const u16* Al = which ? wb_l : waT_l;
  const u16* Bh = which ? wvT_h : wqT_h;
  const u16* Bl = which ? wvT_l : wqT_l;
  const int obase = which ? 1024 : 512;
  const int t = threadIdx.x, lane = t & 63, w = t >> 6;
  const int wr = w >> 1, wc = w & 1, ql = lane & 15, g = lane >> 4;
  const f4 fzero = {0.f, 0.f, 0.f, 0.f};
  f4 acc[4][4];
#pragma unroll
  for (int i = 0; i < 4; ++i)
#pragma unroll
    for (int j = 0; j < 4; ++j) acc[i][j] = fzero;

  for (int ks = 0; ks < 8; ++ks) {
    __syncthreads();
    stage_tile(&Ah[(size_t)r0 * 512 + ks * 64], 512, lah, t);
    stage_tile(&Al[(size_t)r0 * 512 + ks * 64], 512, lal, t);
    stage_tile(&Bh[(size_t)c0 * 512 + ks * 64], 512, lbh, t);
    stage_tile(&Bl[(size_t)c0 * 512 + ks * 64], 512, lbl, t);
    __syncthreads();
#pragma unroll
    for (int kk = 0; kk < 2; ++kk) {
      b16x8 ah[4], al[4], bh[4], bl[4];
#pragma unroll
      for (int rt = 0; rt < 4; ++rt) {
        ah[rt] = readfrag(lah, wr * 64 + rt * 16 + ql, kk, g);
        al[rt] = readfrag(lal, wr * 64 + rt * 16 + ql, kk, g);
      }
#pragma unroll
      for (int ct = 0; ct < 4; ++ct) {
        bh[ct] = readfrag(lbh, wc * 64 + ct * 16 + ql, kk, g);
        bl[ct] = readfrag(lbl, wc * 64 + ct * 16 + ql, kk, g);
      }
#pragma unroll
      for (int rt = 0; rt < 4; ++rt)
#pragma unroll
        for (int ct = 0; ct < 4; ++ct)
          acc[rt][ct] = mfma3(ah[rt], al[rt], bh[ct], bl[ct], acc[rt][ct]);
    }
  }
#pragma unroll
  for (int rt = 0; rt < 4; ++rt) {
#pragma unroll
    for (int ct = 0; ct < 4; ++ct) {
      f4 v = acc[rt][ct];
      int col = c0 + wc * 64 + ct * 16 + ql;
      int rowb = r0 + wr * 64 + rt * 16 + g * 4;
#pragma unroll
      for (int r = 0; r < 4; ++r)
        wh[(size_t)(obase + rowb + r) * 1024 + col] = f2bf(v[r]);
    }
  }
}

// ---------------------------------------------------------------------------
// K2: projection GEMM (unchanged r13). Grid 384.
__global__ __launch_bounds__(512, 2) void k_proj(
    const u16* __restrict__ xh, const u16* __restrict__ wh,
    u16* __restrict__ kh, u16* __restrict__ ph, u16* __restrict__ ut) {
  __shared__ u16 lA[2 * 16384], lB[2 * 8192];    // 96 KB
  const int bid = blockIdx.x;
  const int t = threadIdx.x, lane = t & 63, w = t >> 6;
  const int wr = w >> 1, wc = w & 1, ql = lane & 15, g = lane >> 4;
  const f4 fzero = {0.f, 0.f, 0.f, 0.f};
  f4 acc[4][4];
#pragma unroll
  for (int i = 0; i < 4; ++i)
#pragma unroll
    for (int j = 0; j < 4; ++j) acc[i][j] = fzero;

  const bool kp = bid < 256;
  int Mt, Nt;
  const u16 *Ab, *Bb;
  if (kp) {
    Mt = bid >> 6;                         // 0..3
    Nt = bid & 63;                         // 0..63
    Ab = wh + (size_t)(Mt * 256) * 1024;
    Bb = xh + (size_t)(Nt * 128) * 1024;
  } else {
    int b2 = bid - 256;
    Mt = b2 >> 2;                          // 0..31
    Nt = b2 & 3;                           // 0..3
    Ab = xh + (size_t)(Mt * 256) * 1024;
    Bb = wh + (size_t)(1024 + Nt * 128) * 1024;
  }
  gemm_core<16>(Ab, 1024, Bb, 1024, lA, lB, t, wr, wc, ql, g, acc);

  if (kp) {
#pragma unroll
    for (int rt = 0; rt < 4; ++rt) {
#pragma unroll
      for (int ct = 0; ct < 4; ++ct) {
        f4 v = acc[rt][ct];
        int f = Mt * 256 + wr * 64 + rt * 16 + g * 4;
        int s = Nt * 128 + wc * 64 + ct * 16 + ql;
        ushort4 hh;
        hh.x = f2bf(v[0]); hh.y = f2bf(v[1]); hh.z = f2bf(v[2]); hh.w = f2bf(v[3]);
        if (f < 512) *(ushort4*)&kh[(size_t)s * 512 + f] = hh;
        else         *(ushort4*)&ph[(size_t)s * 512 + (f - 512)] = hh;
      }
    }
  } else {
#pragma unroll
    for (int rt = 0; rt < 4; ++rt) {
#pragma unroll
      for (int ct = 0; ct < 4; ++ct) {
        f4 v = acc[rt][ct];
        int s = Mt * 256 + wr * 64 + rt * 16 + g * 4;
        int d = Nt * 128 + wc * 64 + ct * 16 + ql;
        int bb = s >> 11, k0 = s & 2047;
        ushort4 hh;
        hh.x = f2bf(v[0]); hh.y = f2bf(v[1]); hh.z = f2bf(v[2]); hh.w = f2bf(v[3]);
        *(ushort4*)&ut[((size_t)bb * 512 + d) * 2048 + k0] = hh;
      }
    }
  }
}

// ---------------------------------------------------------------------------
// K3: score GEMM (unchanged r13). Grid 512 (two full rounds, tail-free).
__global__ __launch_bounds__(512, 2) void k_score(
    const u16* __restrict__ ph, const u16* __restrict__ kh,
    u16* __restrict__ probs, float* __restrict__ l) {
  constexpr float INVT = 0.04419417382415922f;  // 1/sqrt(512)
  __shared__ u16 lA[2 * 16384], lB[2 * 8192];
  const int bid = blockIdx.x;
  const int b = bid >> 7, rem = bid & 127;
  const int Mt = rem >> 4, Nt = rem & 15;
  const int k0b = Mt * 256, q0b = Nt * 128;
  const int t = threadIdx.x, lane = t & 63, w = t >> 6;
  const int wr = w >> 1, wc = w & 1, ql = lane & 15, g = lane >> 4;
  const f4 fzero = {0.f, 0.f, 0.f, 0.f};
  f4 acc[4][4];
#pragma unroll
  for (int i = 0; i < 4; ++i)
#pragma unroll
    for (int j = 0; j < 4; ++j) acc[i][j] = fzero;

  const u16* Ab = &kh[((size_t)b * 2048 + k0b) * 512];
  const u16* Bb = &ph[((size_t)b * 2048 + q0b) * 512];
  gemm_core<8>(Ab, 512, Bb, 512, lA, lB, t, wr, wc, ql, g, acc);

  float lq[4] = {0.f, 0.f, 0.f, 0.f};
#pragma unroll
  for (int rt = 0; rt < 4; ++rt) {
    int kr = k0b + wr * 64 + rt * 16 + g * 4;
#pragma unroll
    for (int ct = 0; ct < 4; ++ct) {
      int q = q0b + wc * 64 + ct * 16 + ql;
      f4 a = acc[rt][ct];
      float p0 = __expf(a[0] * INVT), p1 = __expf(a[1] * INVT);
      float p2 = __expf(a[2] * INVT), p3 = __expf(a[3] * INVT);
      ushort4 hh;
      hh.x = f2bf(p0); hh.y = f2bf(p1); hh.z = f2bf(p2); hh.w = f2bf(p3);
      *(ushort4*)&probs[((size_t)b * 2048 + q) * 2048 + kr] = hh;
      lq[ct] += (p0 + p1) + (p2 + p3);
    }
  }
#pragma unroll
  for (int ct = 0; ct < 4; ++ct) {
    float s = lq[ct];
    s += __shfl_xor(s, 16);
    s += __shfl_xor(s, 32);
    if (lane < 16) atomicAdd(&l[b * 2048 + q0b + wc * 64 + ct * 16 + lane], s);
  }
}

// ---------------------------------------------------------------------------
// K4: output GEMM, r15: 128x128 tiles, grid 256 (full CU coverage), 4-wave
// blocks, per-wave 64x64, K=2048 (NT=32), LDS 64KB.
// A=ut[d][k], B=probs[q][k] -> C[d][q]; out[b][q][d] = v / l[q], float4.
__global__ __launch_bounds__(256, 2) void k_out(
    const u16* __restrict__ ut, const u16* __restrict__ probs,
    const float* __restrict__ l, float* __restrict__ out) {
  __shared__ u16 lA[2 * 8192], lB[2 * 8192];     // 64 KB
  const int bid = blockIdx.x;
  const int b = bid >> 6, rem = bid & 63;
  const int Mt = rem >> 4, Nt = rem & 15;        // d-tile 0..3, q-tile 0..15
  const int d0 = Mt * 128, q0 = Nt * 128;
  const int t = threadIdx.x, lane = t & 63, w = t >> 6;
  const int wr = w >> 1, wc = w & 1, ql = lane & 15, g = lane >> 4;
  const f4 fzero = {0.f, 0.f, 0.f, 0.f};
  f4 acc[4][4];
#pragma unroll
  for (int i = 0; i < 4; ++i)
#pragma unroll
    for (int j = 0; j < 4; ++j) acc[i][j] = fzero;

  const u16* Ab = &ut[((size_t)b * 512 + d0) * 2048];
  const u16* Bb = &probs[((size_t)b * 2048 + q0) * 2048];
  gemm_core128<32>(Ab, 2048, Bb, 2048, lA, lB, t, wr, wc, ql, g, acc);

#pragma unroll
  for (int ct = 0; ct < 4; ++ct) {
    int q = q0 + wc * 64 + ct * 16 + ql;
    float inv = 1.0f / l[b * 2048 + q];
    size_t orow = ((size_t)b * 2048 + q) * 512;
#pragma unroll
    for (int rt = 0; rt < 4; ++rt) {
      int d = d0 + wr * 64 + rt * 16 + g * 4;
      f4 v = acc[rt][ct] * inv;
      *(f4*)&out[orow + d] = v;
    }
  }
}

// ---------------------------------------------------------------------------
extern "C" void kernel_launch(void* const* d_in, const int* in_sizes, int n_in,
                              void* d_out, int out_size, void* d_ws, size_t ws_size,
                              hipStream_t stream) {
  const float* x = (const float*)d_in[0];
  const float* Wk = (const float*)d_in[1];
  const float* Wq = (const float*)d_in[2];
  const float* Wv = (const float*)d_in[3];
  const float* Wa = (const float*)d_in[4];
  const float* Wb = (const float*)d_in[5];
  float* out = (float*)d_out;

  char* ws = (char*)d_ws;
  size_t off = 0;
  auto alloc = [&](size_t bytes) -> void* {
    void* p = ws + off;
    off += (bytes + 255) & ~(size_t)255;
    return p;
  };
  u16* wh = (u16*)alloc((size_t)1536 * 1024 * 2);
  u16* xh = (u16*)alloc((size_t)8192 * 1024 * 2);
  u16* kh = (u16*)alloc((size_t)8192 * 512 * 2);
  u16* ph = (u16*)alloc((size_t)8192 * 512 * 2);
  u16* ut = (u16*)alloc((size_t)8192 * 512 * 2);
  u16* probs = (u16*)alloc((size_t)4 * 2048 * 2048 * 2);
  float* l = (float*)alloc(8192 * 4);
  u16* waT_h = (u16*)alloc((size_t)512 * 512 * 2);
  u16* waT_l = (u16*)alloc((size_t)512 * 512 * 2);
  u16* wqT_h = (u16*)alloc((size_t)1024 * 512 * 2);
  u16* wqT_l = (u16*)alloc((size_t)1024 * 512 * 2);
  u16* wb_h = (u16*)alloc((size_t)512 * 512 * 2);
  u16* wb_l = (u16*)alloc((size_t)512 * 512 * 2);
  u16* wvT_h = (u16*)alloc((size_t)1024 * 512 * 2);
  u16* wvT_l = (u16*)alloc((size_t)1024 * 512 * 2);
  (void)ws_size; (void)in_sizes; (void)n_in; (void)out_size;

  hipLaunchKernelGGL(k_prep, dim3(9288), dim3(256), 0, stream,
                     x, Wk, Wq, Wv, Wa, Wb, xh, wh,
                     waT_h, waT_l, wqT_h, wqT_l, wb_h, wb_l, wvT_h, wvT_l, l);
  hipLaunchKernelGGL(k_fold_mfma, dim3(64), dim3(256), 0, stream,
                     waT_h, waT_l, wqT_h, wqT_l, wb_h, wb_l, wvT_h, wvT_l, wh);
  hipLaunchKernelGGL(k_proj, dim3(384), dim3(512), 0, stream, xh, wh, kh, ph, ut);
  hipLaunchKernelGGL(k_score, dim3(512), dim3(512), 0, stream, ph, kh, probs, l);
  hipLaunchKernelGGL(k_out, dim3(256), dim3(256), 0, stream, ut, probs, l, out);
}

// Round 16
// 122.778 us; speedup vs baseline: 1.1722x; 1.0474x over previous
//
#include <hip/hip_runtime.h>

// SelfAttention_33852932227207 — MI355X, round 16.
// e = x^T (Wq^T Wa Wk) x / sqrt(512);  out = softmax(e) @ (x (Wb Wv)^T).
// r16 (inner GEMM schedules frozen at the r13 structures):
//  1) k_fold fused with the x-conversion (independent work): fold's 64-block
//     25%-occupancy GEMM hides under the 8192-block x pass. Prep split into
//     k_prep_w (weights + l zero) -> k_fx (fold || x-convert).
//  2) k_out: split-K within the block. 512 thr = two 4-wave groups, group g
//     runs the identical gemm_core128 pipeline (NT=16) on k half g with its
//     own 64KB LDS partition (barrier counts identical across groups);
//     fp32 cross-group add via LDS. Halves the serial k-depth.
// k_proj / k_score unchanged from r13/r15.

typedef __attribute__((ext_vector_type(8))) short b16x8;
typedef __attribute__((ext_vector_type(4))) float f4;
typedef unsigned short u16;

#define DEVINL __device__ __forceinline__

DEVINL u16 f2bf(float f) {               // fp32 -> bf16 RNE
  unsigned int u = __float_as_uint(f);
  u = u + 0x7FFFu + ((u >> 16) & 1u);
  return (u16)(u >> 16);
}
DEVINL float bf2f(u16 h) { return __uint_as_float(((unsigned int)h) << 16); }

DEVINL f4 mfma_(b16x8 a, b16x8 b, f4 c) {
  return __builtin_amdgcn_mfma_f32_16x16x32_bf16(a, b, c, 0, 0, 0);
}
// bf16x3: (ah+al)*(bh+bl) ~= ah*bh + ah*bl + al*bh
DEVINL f4 mfma3(b16x8 ah, b16x8 al, b16x8 bh, b16x8 bl, f4 c) {
  c = mfma_(ah, bh, c);
  c = mfma_(ah, bl, c);
  c = mfma_(al, bh, c);
  return c;
}
DEVINL void gload16(const u16* g, u16* l) {
  __builtin_amdgcn_global_load_lds(
      (const __attribute__((address_space(1))) void*)g,
      (__attribute__((address_space(3))) void*)l, 16, 0, 0);
}

// ---- 16B-chunk XOR swizzle tile helpers (r5-proven, bank-conflict=0).
DEVINL void stage_tile(const u16* __restrict__ gbase, int rstride,
                       u16* __restrict__ lds, int t) {      // 128x64, 256 thr
#pragma unroll
  for (int r = 0; r < 4; ++r) {
    int cp = r * 256 + t;
    int row = cp >> 3, j = cp & 7;
    int jj = j ^ (row & 7);
    gload16(&gbase[(size_t)row * rstride + jj * 8], &lds[cp * 8]);
  }
}
DEVINL void stageA256(const u16* __restrict__ gbase, int rstride,
                      u16* __restrict__ lds, int t) {       // 256x64, 512 thr
#pragma unroll
  for (int r = 0; r < 4; ++r) {
    int cp = r * 512 + t;                // 2048 chunks
    int row = cp >> 3, j = cp & 7;
    int jj = j ^ (row & 7);
    gload16(&gbase[(size_t)row * rstride + jj * 8], &lds[cp * 8]);
  }
}
DEVINL void stageB128(const u16* __restrict__ gbase, int rstride,
                      u16* __restrict__ lds, int t) {       // 128x64, 512 thr
#pragma unroll
  for (int r = 0; r < 2; ++r) {
    int cp = r * 512 + t;                // 1024 chunks
    int row = cp >> 3, j = cp & 7;
    int jj = j ^ (row & 7);
    gload16(&gbase[(size_t)row * rstride + jj * 8], &lds[cp * 8]);
  }
}
DEVINL b16x8 readfrag(const u16* __restrict__ lds, int row, int kk, int g) {
  int chunk = row * 8 + ((kk * 4 + g) ^ (row & 7));
  return *(const b16x8*)&lds[chunk * 8];
}

// ---- r13 core: 256x128 BK=64 8-wave, reads-one-half-ahead (k_proj/k_score).
template <int NT>
DEVINL void gemm_core(const u16* __restrict__ Ab, int sA,
                      const u16* __restrict__ Bb, int sB,
                      u16* __restrict__ ldsA, u16* __restrict__ ldsB,
                      int t, int wr, int wc, int ql, int g, f4 acc[4][4]) {
  b16x8 fa[4], fb[4];
  b16x8 ga[4], gb[4];
  stageA256(Ab, sA, ldsA, t);
  stageB128(Bb, sB, ldsB, t);
  stageA256(Ab + 64, sA, ldsA + 16384, t);
  stageB128(Bb + 64, sB, ldsB + 8192, t);
  asm volatile("s_waitcnt vmcnt(6)" ::: "memory");
  __builtin_amdgcn_s_barrier();
  asm volatile("" ::: "memory");
  u16 *cA = ldsA, *cB = ldsB, *nA = ldsA + 16384, *nB = ldsB + 8192;
#pragma unroll
  for (int i = 0; i < 4; ++i) {
    fa[i] = readfrag(cA, wr * 64 + i * 16 + ql, 0, g);
    fb[i] = readfrag(cB, wc * 64 + i * 16 + ql, 0, g);
  }
  for (int j = 0; j < NT; ++j) {
#pragma unroll
    for (int i = 0; i < 4; ++i) {
      ga[i] = readfrag(cA, wr * 64 + i * 16 + ql, 1, g);
      gb[i] = readfrag(cB, wc * 64 + i * 16 + ql, 1, g);
    }
    __builtin_amdgcn_s_setprio(1);
#pragma unroll
    for (int rt = 0; rt < 4; ++rt)
#pragma unroll
      for (int ct = 0; ct < 4; ++ct)
        acc[rt][ct] = mfma_(fa[rt], fb[ct], acc[rt][ct]);
    __builtin_amdgcn_s_setprio(0);
    asm volatile("s_waitcnt vmcnt(0)" ::: "memory");
    __builtin_amdgcn_s_barrier();
    asm volatile("" ::: "memory");
    if (j + 1 < NT) {
#pragma unroll
      for (int i = 0; i < 4; ++i) {
        fa[i] = readfrag(nA, wr * 64 + i * 16 + ql, 0, g);
        fb[i] = readfrag(nB, wc * 64 + i * 16 + ql, 0, g);
      }
    }
    if (j + 2 < NT) {
      stageA256(Ab + (j + 2) * 64, sA, cA, t);
      stageB128(Bb + (j + 2) * 64, sB, cB, t);
    }
    __builtin_amdgcn_s_setprio(1);
#pragma unroll
    for (int rt = 0; rt < 4; ++rt)
#pragma unroll
      for (int ct = 0; ct < 4; ++ct)
        acc[rt][ct] = mfma_(ga[rt], gb[ct], acc[rt][ct]);
    __builtin_amdgcn_s_setprio(0);
    u16* tmp = cA; cA = nA; nA = tmp;
    tmp = cB; cB = nB; nB = tmp;
  }
}

// ---- r15 core: 128x128 BK=64, 4-wave group (256 thr), same discipline.
template <int NT>
DEVINL void gemm_core128(const u16* __restrict__ Ab, int sA,
                         const u16* __restrict__ Bb, int sB,
                         u16* __restrict__ ldsA, u16* __restrict__ ldsB,
                         int t, int wr, int wc, int ql, int g, f4 acc[4][4]) {
  b16x8 fa[4], fb[4];
  b16x8 ga[4], gb[4];
  stage_tile(Ab, sA, ldsA, t);
  stage_tile(Bb, sB, ldsB, t);
  stage_tile(Ab + 64, sA, ldsA + 8192, t);
  stage_tile(Bb + 64, sB, ldsB + 8192, t);
  asm volatile("s_waitcnt vmcnt(8)" ::: "memory");
  __builtin_amdgcn_s_barrier();
  asm volatile("" ::: "memory");
  u16 *cA = ldsA, *cB = ldsB, *nA = ldsA + 8192, *nB = ldsB + 8192;
#pragma unroll
  for (int i = 0; i < 4; ++i) {
    fa[i] = readfrag(cA, wr * 64 + i * 16 + ql, 0, g);
    fb[i] = readfrag(cB, wc * 64 + i * 16 + ql, 0, g);
  }
  for (int j = 0; j < NT; ++j) {
#pragma unroll
    for (int i = 0; i < 4; ++i) {
      ga[i] = readfrag(cA, wr * 64 + i * 16 + ql, 1, g);
      gb[i] = readfrag(cB, wc * 64 + i * 16 + ql, 1, g);
    }
    __builtin_amdgcn_s_setprio(1);
#pragma unroll
    for (int rt = 0; rt < 4; ++rt)
#pragma unroll
      for (int ct = 0; ct < 4; ++ct)
        acc[rt][ct] = mfma_(fa[rt], fb[ct], acc[rt][ct]);
    __builtin_amdgcn_s_setprio(0);
    asm volatile("s_waitcnt vmcnt(0)" ::: "memory");
    __builtin_amdgcn_s_barrier();
    asm volatile("" ::: "memory");
    if (j + 1 < NT) {
#pragma unroll
      for (int i = 0; i < 4; ++i) {
        fa[i] = readfrag(nA, wr * 64 + i * 16 + ql, 0, g);
        fb[i] = readfrag(nB, wc * 64 + i * 16 + ql, 0, g);
      }
    }
    if (j + 2 < NT) {
      stage_tile(Ab + (j + 2) * 64, sA, cA, t);
      stage_tile(Bb + (j + 2) * 64, sB, cB, t);
    }
    __builtin_amdgcn_s_setprio(1);
#pragma unroll
    for (int rt = 0; rt < 4; ++rt)
#pragma unroll
      for (int ct = 0; ct < 4; ++ct)
        acc[rt][ct] = mfma_(ga[rt], gb[ct], acc[rt][ct]);
    __builtin_amdgcn_s_setprio(0);
    u16* tmp = cA; cA = nA; nA = tmp;
    tmp = cB; cB = nB; nB = tmp;
  }
}

// ---------------------------------------------------------------------------
// K0: weight prep + l zero. Grid 1096.
//  [0,512): Wk->wh rows 0..511; [512,768): Wb hi/lo; [768,1088): transposes;
//  [1088,1096): l = 0.
__global__ __launch_bounds__(256) void k_prep_w(
    const float* __restrict__ Wk, const float* __restrict__ Wq,
    const float* __restrict__ Wv, const float* __restrict__ Wa,
    const float* __restrict__ Wb, u16* __restrict__ wh,
    u16* __restrict__ waT_h, u16* __restrict__ waT_l,
    u16* __restrict__ wqT_h, u16* __restrict__ wqT_l,
    u16* __restrict__ wb_h, u16* __restrict__ wb_l,
    u16* __restrict__ wvT_h, u16* __restrict__ wvT_l,
    float* __restrict__ l) {
  const int bid = blockIdx.x, t = threadIdx.x;
  if (bid < 512) {
    int i = bid * 256 + t;
    float4 v = ((const float4*)Wk)[i];
    ushort4 h;
    h.x = f2bf(v.x); h.y = f2bf(v.y); h.z = f2bf(v.z); h.w = f2bf(v.w);
    ((ushort4*)wh)[i] = h;
    return;
  }
  if (bid < 768) {
    int i = (bid - 512) * 256 + t;
    float4 v = ((const float4*)Wb)[i];
    ushort4 h, lo;
    h.x = f2bf(v.x); lo.x = f2bf(v.x - bf2f(h.x));
    h.y = f2bf(v.y); lo.y = f2bf(v.y - bf2f(h.y));
    h.z = f2bf(v.z); lo.z = f2bf(v.z - bf2f(h.z));
    h.w = f2bf(v.w); lo.w = f2bf(v.w - bf2f(h.w));
    ((ushort4*)wb_h)[i] = h;
    ((ushort4*)wb_l)[i] = lo;
    return;
  }
  if (bid >= 1088) {
    int i = (bid - 1088) * 256 + t;
    float4 z = {0.f, 0.f, 0.f, 0.f};
    ((float4*)l)[i] = z;
    return;
  }
  __shared__ float ftile[64][68];
  const int tb = bid - 768;              // 0..319
  const float* src;
  u16 *dh, *dl;
  int S, m0, c0;
  if (tb < 64) {
    src = Wa; dh = waT_h; dl = waT_l; S = 512;
    m0 = (tb >> 3) * 64; c0 = (tb & 7) * 64;
  } else if (tb < 192) {
    int q = tb - 64;
    src = Wq; dh = wqT_h; dl = wqT_l; S = 1024;
    m0 = (q >> 4) * 64; c0 = (q & 15) * 64;
  } else {
    int q = tb - 192;
    src = Wv; dh = wvT_h; dl = wvT_l; S = 1024;
    m0 = (q >> 4) * 64; c0 = (q & 15) * 64;
  }
  {
    int i = t >> 4, j4 = (t & 15) * 4;
#pragma unroll
    for (int ii = 0; ii < 4; ++ii) {
      int row = i + ii * 16;
      float4 v = *(const float4*)&src[(size_t)(m0 + row) * S + c0 + j4];
      ftile[row][j4] = v.x; ftile[row][j4 + 1] = v.y;
      ftile[row][j4 + 2] = v.z; ftile[row][j4 + 3] = v.w;
    }
  }
  __syncthreads();
  {
    int oc = t >> 2, mc = (t & 3) * 16;
#pragma unroll
    for (int j = 0; j < 4; ++j) {
      int m = mc + j * 4;
      float v0 = ftile[m][oc], v1 = ftile[m + 1][oc];
      float v2 = ftile[m + 2][oc], v3 = ftile[m + 3][oc];
      ushort4 h, lo;
      h.x = f2bf(v0); lo.x = f2bf(v0 - bf2f(h.x));
      h.y = f2bf(v1); lo.y = f2bf(v1 - bf2f(h.y));
      h.z = f2bf(v2); lo.z = f2bf(v2 - bf2f(h.z));
      h.w = f2bf(v3); lo.w = f2bf(v3 - bf2f(h.w));
      size_t o = (size_t)(c0 + oc) * 512 + m0 + m;
      *(ushort4*)&dh[o] = h;
      *(ushort4*)&dl[o] = lo;
    }
  }
}

// ---------------------------------------------------------------------------
// K1: fused fold + x-conversion. Grid 8256: bid<64 = fold GEMM (bf16x3),
// bid>=64 = x fp32->bf16 (independent of fold inputs).
__global__ __launch_bounds__(256) void k_fx(
    const float* __restrict__ x,
    const u16* __restrict__ waT_h, const u16* __restrict__ waT_l,
    const u16* __restrict__ wqT_h, const u16* __restrict__ wqT_l,
    const u16* __restrict__ wb_h, const u16* __restrict__ wb_l,
    const u16* __restrict__ wvT_h, const u16* __restrict__ wvT_l,
    u16* __restrict__ xh, u16* __restrict__ wh) {
  const int bid = blockIdx.x, t = threadIdx.x;
  if (bid >= 64) {                       // x conversion
    int i = (bid - 64) * 256 + t;
    float4 v = ((const float4*)x)[i];
    ushort4 h;
    h.x = f2bf(v.x); h.y = f2bf(v.y); h.z = f2bf(v.z); h.w = f2bf(v.w);
    ((ushort4*)xh)[i] = h;
    return;
  }
  // fold GEMM (identical to r13 k_fold_mfma)
  __shared__ u16 lah[8192], lal[8192], lbh[8192], lbl[8192];
  const int which = bid >> 5;
  const int idx = bid & 31;
  const int r0 = (idx >> 3) * 128, c0 = (idx & 7) * 128;
  const u16* Ah = which ? wb_h : waT_h;
  const u16* Al = which ? wb_l : waT_l;
  const u16* Bh = which ? wvT_h : wqT_h;
  const u16* Bl = which ? wvT_l : wqT_l;
  const int obase = which ? 1024 : 512;
  const int lane = t & 63, w = t >> 6;
  const int wr = w >> 1, wc = w & 1, ql = lane & 15, g = lane >> 4;
  const f4 fzero = {0.f, 0.f, 0.f, 0.f};
  f4 acc[4][4];
#pragma unroll
  for (int i = 0; i < 4; ++i)
#pragma unroll
    for (int j = 0; j < 4; ++j) acc[i][j] = fzero;

  for (int ks = 0; ks < 8; ++ks) {
    __syncthreads();
    stage_tile(&Ah[(size_t)r0 * 512 + ks * 64], 512, lah, t);
    stage_tile(&Al[(size_t)r0 * 512 + ks * 64], 512, lal, t);
    stage_tile(&Bh[(size_t)c0 * 512 + ks * 64], 512, lbh, t);
    stage_tile(&Bl[(size_t)c0 * 512 + ks * 64], 512, lbl, t);
    __syncthreads();
#pragma unroll
    for (int kk = 0; kk < 2; ++kk) {
      b16x8 ah[4], al[4], bh[4], bl[4];
#pragma unroll
      for (int rt = 0; rt < 4; ++rt) {
        ah[rt] = readfrag(lah, wr * 64 + rt * 16 + ql, kk, g);
        al[rt] = readfrag(lal, wr * 64 + rt * 16 + ql, kk, g);
      }
#pragma unroll
      for (int ct = 0; ct < 4; ++ct) {
        bh[ct] = readfrag(lbh, wc * 64 + ct * 16 + ql, kk, g);
        bl[ct] = readfrag(lbl, wc * 64 + ct * 16 + ql, kk, g);
      }
#pragma unroll
      for (int rt = 0; rt < 4; ++rt)
#pragma unroll
        for (int ct = 0; ct < 4; ++ct)
          acc[rt][ct] = mfma3(ah[rt], al[rt], bh[ct], bl[ct], acc[rt][ct]);
    }
  }
#pragma unroll
  for (int rt = 0; rt < 4; ++rt) {
#pragma unroll
    for (int ct = 0; ct < 4; ++ct) {
      f4 v = acc[rt][ct];
      int col = c0 + wc * 64 + ct * 16 + ql;
      int rowb = r0 + wr * 64 + rt * 16 + g * 4;
#pragma unroll
      for (int r = 0; r < 4; ++r)
        wh[(size_t)(obase + rowb + r) * 1024 + col] = f2bf(v[r]);
    }
  }
}

// ---------------------------------------------------------------------------
// K2: projection GEMM (unchanged r13). Grid 384.
__global__ __launch_bounds__(512, 2) void k_proj(
    const u16* __restrict__ xh, const u16* __restrict__ wh,
    u16* __restrict__ kh, u16* __restrict__ ph, u16* __restrict__ ut) {
  __shared__ u16 lA[2 * 16384], lB[2 * 8192];    // 96 KB
  const int bid = blockIdx.x;
  const int t = threadIdx.x, lane = t & 63, w = t >> 6;
  const int wr = w >> 1, wc = w & 1, ql = lane & 15, g = lane >> 4;
  const f4 fzero = {0.f, 0.f, 0.f, 0.f};
  f4 acc[4][4];
#pragma unroll
  for (int i = 0; i < 4; ++i)
#pragma unroll
    for (int j = 0; j < 4; ++j) acc[i][j] = fzero;

  const bool kp = bid < 256;
  int Mt, Nt;
  const u16 *Ab, *Bb;
  if (kp) {
    Mt = bid >> 6;                         // 0..3
    Nt = bid & 63;                         // 0..63
    Ab = wh + (size_t)(Mt * 256) * 1024;
    Bb = xh + (size_t)(Nt * 128) * 1024;
  } else {
    int b2 = bid - 256;
    Mt = b2 >> 2;                          // 0..31
    Nt = b2 & 3;                           // 0..3
    Ab = xh + (size_t)(Mt * 256) * 1024;
    Bb = wh + (size_t)(1024 + Nt * 128) * 1024;
  }
  gemm_core<16>(Ab, 1024, Bb, 1024, lA, lB, t, wr, wc, ql, g, acc);

  if (kp) {
#pragma unroll
    for (int rt = 0; rt < 4; ++rt) {
#pragma unroll
      for (int ct = 0; ct < 4; ++ct) {
        f4 v = acc[rt][ct];
        int f = Mt * 256 + wr * 64 + rt * 16 + g * 4;
        int s = Nt * 128 + wc * 64 + ct * 16 + ql;
        ushort4 hh;
        hh.x = f2bf(v[0]); hh.y = f2bf(v[1]); hh.z = f2bf(v[2]); hh.w = f2bf(v[3]);
        if (f < 512) *(ushort4*)&kh[(size_t)s * 512 + f] = hh;
        else         *(ushort4*)&ph[(size_t)s * 512 + (f - 512)] = hh;
      }
    }
  } else {
#pragma unroll
    for (int rt = 0; rt < 4; ++rt) {
#pragma unroll
      for (int ct = 0; ct < 4; ++ct) {
        f4 v = acc[rt][ct];
        int s = Mt * 256 + wr * 64 + rt * 16 + g * 4;
        int d = Nt * 128 + wc * 64 + ct * 16 + ql;
        int bb = s >> 11, k0 = s & 2047;
        ushort4 hh;
        hh.x = f2bf(v[0]); hh.y = f2bf(v[1]); hh.z = f2bf(v[2]); hh.w = f2bf(v[3]);
        *(ushort4*)&ut[((size_t)bb * 512 + d) * 2048 + k0] = hh;
      }
    }
  }
}

// ---------------------------------------------------------------------------
// K3: score GEMM (unchanged r13). Grid 512 (two full rounds, tail-free).
__global__ __launch_bounds__(512, 2) void k_score(
    const u16* __restrict__ ph, const u16* __restrict__ kh,
    u16* __restrict__ probs, float* __restrict__ l) {
  constexpr float INVT = 0.04419417382415922f;  // 1/sqrt(512)
  __shared__ u16 lA[2 * 16384], lB[2 * 8192];
  const int bid = blockIdx.x;
  const int b = bid >> 7, rem = bid & 127;
  const int Mt = rem >> 4, Nt = rem & 15;
  const int k0b = Mt * 256, q0b = Nt * 128;
  const int t = threadIdx.x, lane = t & 63, w = t >> 6;
  const int wr = w >> 1, wc = w & 1, ql = lane & 15, g = lane >> 4;
  const f4 fzero = {0.f, 0.f, 0.f, 0.f};
  f4 acc[4][4];
#pragma unroll
  for (int i = 0; i < 4; ++i)
#pragma unroll
    for (int j = 0; j < 4; ++j) acc[i][j] = fzero;

  const u16* Ab = &kh[((size_t)b * 2048 + k0b) * 512];
  const u16* Bb = &ph[((size_t)b * 2048 + q0b) * 512];
  gemm_core<8>(Ab, 512, Bb, 512, lA, lB, t, wr, wc, ql, g, acc);

  float lq[4] = {0.f, 0.f, 0.f, 0.f};
#pragma unroll
  for (int rt = 0; rt < 4; ++rt) {
    int kr = k0b + wr * 64 + rt * 16 + g * 4;
#pragma unroll
    for (int ct = 0; ct < 4; ++ct) {
      int q = q0b + wc * 64 + ct * 16 + ql;
      f4 a = acc[rt][ct];
      float p0 = __expf(a[0] * INVT), p1 = __expf(a[1] * INVT);
      float p2 = __expf(a[2] * INVT), p3 = __expf(a[3] * INVT);
      ushort4 hh;
      hh.x = f2bf(p0); hh.y = f2bf(p1); hh.z = f2bf(p2); hh.w = f2bf(p3);
      *(ushort4*)&probs[((size_t)b * 2048 + q) * 2048 + kr] = hh;
      lq[ct] += (p0 + p1) + (p2 + p3);
    }
  }
#pragma unroll
  for (int ct = 0; ct < 4; ++ct) {
    float s = lq[ct];
    s += __shfl_xor(s, 16);
    s += __shfl_xor(s, 32);
    if (lane < 16) atomicAdd(&l[b * 2048 + q0b + wc * 64 + ct * 16 + lane], s);
  }
}

// ---------------------------------------------------------------------------
// K4: output GEMM, r16: split-K within block. Grid 256, 512 thr = two 4-wave
// groups; group g runs gemm_core128<16> on k half g with its own 64KB LDS;
// identical barrier sequences across groups; fp32 cross-group add via LDS.
// A=ut[d][k], B=probs[q][k] -> C[d][q]; out[b][q][d] = v / l[q], float4.
__global__ __launch_bounds__(512, 1) void k_out(
    const u16* __restrict__ ut, const u16* __restrict__ probs,
    const float* __restrict__ l, float* __restrict__ out) {
  __shared__ u16 buf[65536];                     // 128 KB
  const int bid = blockIdx.x;
  const int b = bid >> 6, rem = bid & 63;
  const int Mt = rem >> 4, Nt = rem & 15;        // d-tile 0..3, q-tile 0..15
  const int d0 = Mt * 128, q0 = Nt * 128;
  const int t = threadIdx.x;
  const int grp = t >> 8, tl = t & 255;          // k-half, thread-in-group
  const int lane = tl & 63, w = tl >> 6;
  const int wr = w >> 1, wc = w & 1, ql = lane & 15, g = lane >> 4;
  const f4 fzero = {0.f, 0.f, 0.f, 0.f};
  f4 acc[4][4];
#pragma unroll
  for (int i = 0; i < 4; ++i)
#pragma unroll
    for (int j = 0; j < 4; ++j) acc[i][j] = fzero;

  u16* myA = buf + grp * 32768;
  u16* myB = buf + grp * 32768 + 16384;
  const u16* Ab = &ut[((size_t)b * 512 + d0) * 2048 + grp * 1024];
  const u16* Bb = &probs[((size_t)b * 2048 + q0) * 2048 + grp * 1024];
  gemm_core128<16>(Ab, 2048, Bb, 2048, myA, myB, tl, wr, wc, ql, g, acc);

  // cross-group reduce: group1 -> LDS (fp32), group0 adds + stores.
  __syncthreads();
  float* red = (float*)buf;                      // 128x128 fp32 = 64 KB
  if (grp == 1) {
#pragma unroll
    for (int rt = 0; rt < 4; ++rt)
#pragma unroll
      for (int ct = 0; ct < 4; ++ct) {
        int dl = wr * 64 + rt * 16 + g * 4;
        int qlq = wc * 64 + ct * 16 + ql;
#pragma unroll
        for (int r = 0; r < 4; ++r) red[(dl + r) * 128 + qlq] = acc[rt][ct][r];
      }
  }
  __syncthreads();
  if (grp == 0) {
#pragma unroll
    for (int ct = 0; ct < 4; ++ct) {
      int qlq = wc * 64 + ct * 16 + ql;
      int q = q0 + qlq;
      float inv = 1.0f / l[b * 2048 + q];
      size_t orow = ((size_t)b * 2048 + q) * 512;
#pragma unroll
      for (int rt = 0; rt < 4; ++rt) {
        int dl = wr * 64 + rt * 16 + g * 4;
        f4 v;
#pragma unroll
        for (int r = 0; r < 4; ++r) v[r] = acc[rt][ct][r] + red[(dl + r) * 128 + qlq];
        v *= inv;
        *(f4*)&out[orow + d0 + dl] = v;
      }
    }
  }
}

// ---------------------------------------------------------------------------
extern "C" void kernel_launch(void* const* d_in, const int* in_sizes, int n_in,
                              void* d_out, int out_size, void* d_ws, size_t ws_size,
                              hipStream_t stream) {
  const float* x = (const float*)d_in[0];
  const float* Wk = (const float*)d_in[1];
  const float* Wq = (const float*)d_in[2];
  const float* Wv = (const float*)d_in[3];
  const float* Wa = (const float*)d_in[4];
  const float* Wb = (const float*)d_in[5];
  float* out = (float*)d_out;

  char* ws = (char*)d_ws;
  size_t off = 0;
  auto alloc = [&](size_t bytes) -> void* {
    void* p = ws + off;
    off += (bytes + 255) & ~(size_t)255;
    return p;
  };
  u16* wh = (u16*)alloc((size_t)1536 * 1024 * 2);
  u16* xh = (u16*)alloc((size_t)8192 * 1024 * 2);
  u16* kh = (u16*)alloc((size_t)8192 * 512 * 2);
  u16* ph = (u16*)alloc((size_t)8192 * 512 * 2);
  u16* ut = (u16*)alloc((size_t)8192 * 512 * 2);
  u16* probs = (u16*)alloc((size_t)4 * 2048 * 2048 * 2);
  float* l = (float*)alloc(8192 * 4);
  u16* waT_h = (u16*)alloc((size_t)512 * 512 * 2);
  u16* waT_l = (u16*)alloc((size_t)512 * 512 * 2);
  u16* wqT_h = (u16*)alloc((size_t)1024 * 512 * 2);
  u16* wqT_l = (u16*)alloc((size_t)1024 * 512 * 2);
  u16* wb_h = (u16*)alloc((size_t)512 * 512 * 2);
  u16* wb_l = (u16*)alloc((size_t)512 * 512 * 2);
  u16* wvT_h = (u16*)alloc((size_t)1024 * 512 * 2);
  u16* wvT_l = (u16*)alloc((size_t)1024 * 512 * 2);
  (void)ws_size; (void)in_sizes; (void)n_in; (void)out_size;

  hipLaunchKernelGGL(k_prep_w, dim3(1096), dim3(256), 0, stream,
                     Wk, Wq, Wv, Wa, Wb, wh,
                     waT_h, waT_l, wqT_h, wqT_l, wb_h, wb_l, wvT_h, wvT_l, l);
  hipLaunchKernelGGL(k_fx, dim3(8256), dim3(256), 0, stream,
                     x, waT_h, waT_l, wqT_h, wqT_l, wb_h, wb_l, wvT_h, wvT_l,
                     xh, wh);
  hipLaunchKernelGGL(k_proj, dim3(384), dim3(512), 0, stream, xh, wh, kh, ph, ut);
  hipLaunchKernelGGL(k_score, dim3(512), dim3(512), 0, stream, ph, kh, probs, l);
  hipLaunchKernelGGL(k_out, dim3(256), dim3(512), 0, stream, ut, probs, l, out);
}

// Round 17
// 114.802 us; speedup vs baseline: 1.2536x; 1.0695x over previous
//
#include <hip/hip_runtime.h>

// SelfAttention_33852932227207 — MI355X, round 17.
// e = x^T (Wq^T Wa Wk) x / sqrt(512);  out = softmax(e) @ (x (Wb Wv)^T).
// Per-CU GEMM rate is schedule-invariant (~3 TF/CU, shown r7-r14) -> optimize
// work partitioning only:
//  * k_proj: ONE round of 256 equal blocks. Block (Mt,Nt) does its 256fx128s
//    KP tile (gemm_core<16>, unchanged) THEN a 128sx128d U sub-tile (same x
//    panel, L2-warm) with a simple 2-phase loop. Was 384 blocks = 1.5 rounds.
//  * k_score: ONE round of 256 blocks, 256kx256q tiles (per-wave 128x64,
//    acc[8][4], simple 2-phase, BK=64). Was 512 blocks = 2 rounds.
// Per-output k-accumulation order unchanged -> bit-identical (2.441e-4).
// k_prep_w / k_fx / k_out unchanged from r16.

typedef __attribute__((ext_vector_type(8))) short b16x8;
typedef __attribute__((ext_vector_type(4))) float f4;
typedef unsigned short u16;

#define DEVINL __device__ __forceinline__

DEVINL u16 f2bf(float f) {               // fp32 -> bf16 RNE
  unsigned int u = __float_as_uint(f);
  u = u + 0x7FFFu + ((u >> 16) & 1u);
  return (u16)(u >> 16);
}
DEVINL float bf2f(u16 h) { return __uint_as_float(((unsigned int)h) << 16); }

DEVINL f4 mfma_(b16x8 a, b16x8 b, f4 c) {
  return __builtin_amdgcn_mfma_f32_16x16x32_bf16(a, b, c, 0, 0, 0);
}
// bf16x3: (ah+al)*(bh+bl) ~= ah*bh + ah*bl + al*bh
DEVINL f4 mfma3(b16x8 ah, b16x8 al, b16x8 bh, b16x8 bl, f4 c) {
  c = mfma_(ah, bh, c);
  c = mfma_(ah, bl, c);
  c = mfma_(al, bh, c);
  return c;
}
DEVINL void gload16(const u16* g, u16* l) {
  __builtin_amdgcn_global_load_lds(
      (const __attribute__((address_space(1))) void*)g,
      (__attribute__((address_space(3))) void*)l, 16, 0, 0);
}

// ---- 16B-chunk XOR swizzle tile helpers (r5-proven, bank-conflict=0).
DEVINL void stage_tile(const u16* __restrict__ gbase, int rstride,
                       u16* __restrict__ lds, int t) {      // 128x64, 256 thr
#pragma unroll
  for (int r = 0; r < 4; ++r) {
    int cp = r * 256 + t;
    int row = cp >> 3, j = cp & 7;
    int jj = j ^ (row & 7);
    gload16(&gbase[(size_t)row * rstride + jj * 8], &lds[cp * 8]);
  }
}
DEVINL void stageA256(const u16* __restrict__ gbase, int rstride,
                      u16* __restrict__ lds, int t) {       // 256x64, 512 thr
#pragma unroll
  for (int r = 0; r < 4; ++r) {
    int cp = r * 512 + t;                // 2048 chunks
    int row = cp >> 3, j = cp & 7;
    int jj = j ^ (row & 7);
    gload16(&gbase[(size_t)row * rstride + jj * 8], &lds[cp * 8]);
  }
}
DEVINL void stageB128(const u16* __restrict__ gbase, int rstride,
                      u16* __restrict__ lds, int t) {       // 128x64, 512 thr
#pragma unroll
  for (int r = 0; r < 2; ++r) {
    int cp = r * 512 + t;                // 1024 chunks
    int row = cp >> 3, j = cp & 7;
    int jj = j ^ (row & 7);
    gload16(&gbase[(size_t)row * rstride + jj * 8], &lds[cp * 8]);
  }
}
DEVINL b16x8 readfrag(const u16* __restrict__ lds, int row, int kk, int g) {
  int chunk = row * 8 + ((kk * 4 + g) ^ (row & 7));
  return *(const b16x8*)&lds[chunk * 8];
}

// ---- r13 core: 256x128 BK=64 8-wave, reads-one-half-ahead.
template <int NT>
DEVINL void gemm_core(const u16* __restrict__ Ab, int sA,
                      const u16* __restrict__ Bb, int sB,
                      u16* __restrict__ ldsA, u16* __restrict__ ldsB,
                      int t, int wr, int wc, int ql, int g, f4 acc[4][4]) {
  b16x8 fa[4], fb[4];
  b16x8 ga[4], gb[4];
  stageA256(Ab, sA, ldsA, t);
  stageB128(Bb, sB, ldsB, t);
  stageA256(Ab + 64, sA, ldsA + 16384, t);
  stageB128(Bb + 64, sB, ldsB + 8192, t);
  asm volatile("s_waitcnt vmcnt(6)" ::: "memory");
  __builtin_amdgcn_s_barrier();
  asm volatile("" ::: "memory");
  u16 *cA = ldsA, *cB = ldsB, *nA = ldsA + 16384, *nB = ldsB + 8192;
#pragma unroll
  for (int i = 0; i < 4; ++i) {
    fa[i] = readfrag(cA, wr * 64 + i * 16 + ql, 0, g);
    fb[i] = readfrag(cB, wc * 64 + i * 16 + ql, 0, g);
  }
  for (int j = 0; j < NT; ++j) {
#pragma unroll
    for (int i = 0; i < 4; ++i) {
      ga[i] = readfrag(cA, wr * 64 + i * 16 + ql, 1, g);
      gb[i] = readfrag(cB, wc * 64 + i * 16 + ql, 1, g);
    }
    __builtin_amdgcn_s_setprio(1);
#pragma unroll
    for (int rt = 0; rt < 4; ++rt)
#pragma unroll
      for (int ct = 0; ct < 4; ++ct)
        acc[rt][ct] = mfma_(fa[rt], fb[ct], acc[rt][ct]);
    __builtin_amdgcn_s_setprio(0);
    asm volatile("s_waitcnt vmcnt(0)" ::: "memory");
    __builtin_amdgcn_s_barrier();
    asm volatile("" ::: "memory");
    if (j + 1 < NT) {
#pragma unroll
      for (int i = 0; i < 4; ++i) {
        fa[i] = readfrag(nA, wr * 64 + i * 16 + ql, 0, g);
        fb[i] = readfrag(nB, wc * 64 + i * 16 + ql, 0, g);
      }
    }
    if (j + 2 < NT) {
      stageA256(Ab + (j + 2) * 64, sA, cA, t);
      stageB128(Bb + (j + 2) * 64, sB, cB, t);
    }
    __builtin_amdgcn_s_setprio(1);
#pragma unroll
    for (int rt = 0; rt < 4; ++rt)
#pragma unroll
      for (int ct = 0; ct < 4; ++ct)
        acc[rt][ct] = mfma_(ga[rt], gb[ct], acc[rt][ct]);
    __builtin_amdgcn_s_setprio(0);
    u16* tmp = cA; cA = nA; nA = tmp;
    tmp = cB; cB = nB; nB = tmp;
  }
}

// ---- r15 core: 128x128 BK=64, 4-wave group (256 thr), k_out split-K.
template <int NT>
DEVINL void gemm_core128(const u16* __restrict__ Ab, int sA,
                         const u16* __restrict__ Bb, int sB,
                         u16* __restrict__ ldsA, u16* __restrict__ ldsB,
                         int t, int wr, int wc, int ql, int g, f4 acc[4][4]) {
  b16x8 fa[4], fb[4];
  b16x8 ga[4], gb[4];
  stage_tile(Ab, sA, ldsA, t);
  stage_tile(Bb, sB, ldsB, t);
  stage_tile(Ab + 64, sA, ldsA + 8192, t);
  stage_tile(Bb + 64, sB, ldsB + 8192, t);
  asm volatile("s_waitcnt vmcnt(8)" ::: "memory");
  __builtin_amdgcn_s_barrier();
  asm volatile("" ::: "memory");
  u16 *cA = ldsA, *cB = ldsB, *nA = ldsA + 8192, *nB = ldsB + 8192;
#pragma unroll
  for (int i = 0; i < 4; ++i) {
    fa[i] = readfrag(cA, wr * 64 + i * 16 + ql, 0, g);
    fb[i] = readfrag(cB, wc * 64 + i * 16 + ql, 0, g);
  }
  for (int j = 0; j < NT; ++j) {
#pragma unroll
    for (int i = 0; i < 4; ++i) {
      ga[i] = readfrag(cA, wr * 64 + i * 16 + ql, 1, g);
      gb[i] = readfrag(cB, wc * 64 + i * 16 + ql, 1, g);
    }
    __builtin_amdgcn_s_setprio(1);
#pragma unroll
    for (int rt = 0; rt < 4; ++rt)
#pragma unroll
      for (int ct = 0; ct < 4; ++ct)
        acc[rt][ct] = mfma_(fa[rt], fb[ct], acc[rt][ct]);
    __builtin_amdgcn_s_setprio(0);
    asm volatile("s_waitcnt vmcnt(0)" ::: "memory");
    __builtin_amdgcn_s_barrier();
    asm volatile("" ::: "memory");
    if (j + 1 < NT) {
#pragma unroll
      for (int i = 0; i < 4; ++i) {
        fa[i] = readfrag(nA, wr * 64 + i * 16 + ql, 0, g);
        fb[i] = readfrag(nB, wc * 64 + i * 16 + ql, 0, g);
      }
    }
    if (j + 2 < NT) {
      stage_tile(Ab + (j + 2) * 64, sA, cA, t);
      stage_tile(Bb + (j + 2) * 64, sB, cB, t);
    }
    __builtin_amdgcn_s_setprio(1);
#pragma unroll
    for (int rt = 0; rt < 4; ++rt)
#pragma unroll
      for (int ct = 0; ct < 4; ++ct)
        acc[rt][ct] = mfma_(ga[rt], gb[ct], acc[rt][ct]);
    __builtin_amdgcn_s_setprio(0);
    u16* tmp = cA; cA = nA; nA = tmp;
    tmp = cB; cB = nB; nB = tmp;
  }
}

// ---------------------------------------------------------------------------
// K0: weight prep + l zero (unchanged r16). Grid 1096.
__global__ __launch_bounds__(256) void k_prep_w(
    const float* __restrict__ Wk, const float* __restrict__ Wq,
    const float* __restrict__ Wv, const float* __restrict__ Wa,
    const float* __restrict__ Wb, u16* __restrict__ wh,
    u16* __restrict__ waT_h, u16* __restrict__ waT_l,
    u16* __restrict__ wqT_h, u16* __restrict__ wqT_l,
    u16* __restrict__ wb_h, u16* __restrict__ wb_l,
    u16* __restrict__ wvT_h, u16* __restrict__ wvT_l,
    float* __restrict__ l) {
  const int bid = blockIdx.x, t = threadIdx.x;
  if (bid < 512) {
    int i = bid * 256 + t;
    float4 v = ((const float4*)Wk)[i];
    ushort4 h;
    h.x = f2bf(v.x); h.y = f2bf(v.y); h.z = f2bf(v.z); h.w = f2bf(v.w);
    ((ushort4*)wh)[i] = h;
    return;
  }
  if (bid < 768) {
    int i = (bid - 512) * 256 + t;
    float4 v = ((const float4*)Wb)[i];
    ushort4 h, lo;
    h.x = f2bf(v.x); lo.x = f2bf(v.x - bf2f(h.x));
    h.y = f2bf(v.y); lo.y = f2bf(v.y - bf2f(h.y));
    h.z = f2bf(v.z); lo.z = f2bf(v.z - bf2f(h.z));
    h.w = f2bf(v.w); lo.w = f2bf(v.w - bf2f(h.w));
    ((ushort4*)wb_h)[i] = h;
    ((ushort4*)wb_l)[i] = lo;
    return;
  }
  if (bid >= 1088) {
    int i = (bid - 1088) * 256 + t;
    float4 z = {0.f, 0.f, 0.f, 0.f};
    ((float4*)l)[i] = z;
    return;
  }
  __shared__ float ftile[64][68];
  const int tb = bid - 768;
  const float* src;
  u16 *dh, *dl;
  int S, m0, c0;
  if (tb < 64) {
    src = Wa; dh = waT_h; dl = waT_l; S = 512;
    m0 = (tb >> 3) * 64; c0 = (tb & 7) * 64;
  } else if (tb < 192) {
    int q = tb - 64;
    src = Wq; dh = wqT_h; dl = wqT_l; S = 1024;
    m0 = (q >> 4) * 64; c0 = (q & 15) * 64;
  } else {
    int q = tb - 192;
    src = Wv; dh = wvT_h; dl = wvT_l; S = 1024;
    m0 = (q >> 4) * 64; c0 = (q & 15) * 64;
  }
  {
    int i = t >> 4, j4 = (t & 15) * 4;
#pragma unroll
    for (int ii = 0; ii < 4; ++ii) {
      int row = i + ii * 16;
      float4 v = *(const float4*)&src[(size_t)(m0 + row) * S + c0 + j4];
      ftile[row][j4] = v.x; ftile[row][j4 + 1] = v.y;
      ftile[row][j4 + 2] = v.z; ftile[row][j4 + 3] = v.w;
    }
  }
  __syncthreads();
  {
    int oc = t >> 2, mc = (t & 3) * 16;
#pragma unroll
    for (int j = 0; j < 4; ++j) {
      int m = mc + j * 4;
      float v0 = ftile[m][oc], v1 = ftile[m + 1][oc];
      float v2 = ftile[m + 2][oc], v3 = ftile[m + 3][oc];
      ushort4 h, lo;
      h.x = f2bf(v0); lo.x = f2bf(v0 - bf2f(h.x));
      h.y = f2bf(v1); lo.y = f2bf(v1 - bf2f(h.y));
      h.z = f2bf(v2); lo.z = f2bf(v2 - bf2f(h.z));
      h.w = f2bf(v3); lo.w = f2bf(v3 - bf2f(h.w));
      size_t o = (size_t)(c0 + oc) * 512 + m0 + m;
      *(ushort4*)&dh[o] = h;
      *(ushort4*)&dl[o] = lo;
    }
  }
}

// ---------------------------------------------------------------------------
// K1: fused fold + x-conversion (unchanged r16). Grid 8256.
__global__ __launch_bounds__(256) void k_fx(
    const float* __restrict__ x,
    const u16* __restrict__ waT_h, const u16* __restrict__ waT_l,
    const u16* __restrict__ wqT_h, const u16* __restrict__ wqT_l,
    const u16* __restrict__ wb_h, const u16* __restrict__ wb_l,
    const u16* __restrict__ wvT_h, const u16* __restrict__ wvT_l,
    u16* __restrict__ xh, u16* __restrict__ wh) {
  const int bid = blockIdx.x, t = threadIdx.x;
  if (bid >= 64) {                       // x conversion
    int i = (bid - 64) * 256 + t;
    float4 v = ((const float4*)x)[i];
    ushort4 h;
    h.x = f2bf(v.x); h.y = f2bf(v.y); h.z = f2bf(v.z); h.w = f2bf(v.w);
    ((ushort4*)xh)[i] = h;
    return;
  }
  __shared__ u16 lah[8192], lal[8192], lbh[8192], lbl[8192];
  const int which = bid >> 5;
  const int idx = bid & 31;
  const int r0 = (idx >> 3) * 128, c0 = (idx & 7) * 128;
  const u16* Ah = which ? wb_h : waT_h;
  const u16* Al = which ? wb_l : waT_l;
  const u16* Bh = which ? wvT_h : wqT_h;
  const u16* Bl = which ? wvT_l : wqT_l;
  const int obase = which ? 1024 : 512;
  const int lane = t & 63, w = t >> 6;
  const int wr = w >> 1, wc = w & 1, ql = lane & 15, g = lane >> 4;
  const f4 fzero = {0.f, 0.f, 0.f, 0.f};
  f4 acc[4][4];
#pragma unroll
  for (int i = 0; i < 4; ++i)
#pragma unroll
    for (int j = 0; j < 4; ++j) acc[i][j] = fzero;

  for (int ks = 0; ks < 8; ++ks) {
    __syncthreads();
    stage_tile(&Ah[(size_t)r0 * 512 + ks * 64], 512, lah, t);
    stage_tile(&Al[(size_t)r0 * 512 + ks * 64], 512, lal, t);
    stage_tile(&Bh[(size_t)c0 * 512 + ks * 64], 512, lbh, t);
    stage_tile(&Bl[(size_t)c0 * 512 + ks * 64], 512, lbl, t);
    __syncthreads();
#pragma unroll
    for (int kk = 0; kk < 2; ++kk) {
      b16x8 ah[4], al[4], bh[4], bl[4];
#pragma unroll
      for (int rt = 0; rt < 4; ++rt) {
        ah[rt] = readfrag(lah, wr * 64 + rt * 16 + ql, kk, g);
        al[rt] = readfrag(lal, wr * 64 + rt * 16 + ql, kk, g);
      }
#pragma unroll
      for (int ct = 0; ct < 4; ++ct) {
        bh[ct] = readfrag(lbh, wc * 64 + ct * 16 + ql, kk, g);
        bl[ct] = readfrag(lbl, wc * 64 + ct * 16 + ql, kk, g);
      }
#pragma unroll
      for (int rt = 0; rt < 4; ++rt)
#pragma unroll
        for (int ct = 0; ct < 4; ++ct)
          acc[rt][ct] = mfma3(ah[rt], al[rt], bh[ct], bl[ct], acc[rt][ct]);
    }
  }
#pragma unroll
  for (int rt = 0; rt < 4; ++rt) {
#pragma unroll
    for (int ct = 0; ct < 4; ++ct) {
      f4 v = acc[rt][ct];
      int col = c0 + wc * 64 + ct * 16 + ql;
      int rowb = r0 + wr * 64 + rt * 16 + g * 4;
#pragma unroll
      for (int r = 0; r < 4; ++r)
        wh[(size_t)(obase + rowb + r) * 1024 + col] = f2bf(v[r]);
    }
  }
}

// ---------------------------------------------------------------------------
// K2: projection GEMM, r17: ONE round of 256 blocks. Block (Mt,Nt):
//  phase 1 (KP): 256f x 128s tile via gemm_core<16> (A=wh f-rows, B=xh s).
//  phase 2 (U):  128s x 128d sub-tile (s = Nt panel halved? no: s-tile = the
//    SAME 128 x-rows; d-tile = Mt*128), simple 2-phase loop, per-wave 64x32.
__global__ __launch_bounds__(512, 1) void k_proj(
    const u16* __restrict__ xh, const u16* __restrict__ wh,
    u16* __restrict__ kh, u16* __restrict__ ph, u16* __restrict__ ut) {
  __shared__ u16 lA[2 * 16384], lB[2 * 8192];    // 96 KB
  const int bid = blockIdx.x;
  const int Mt = bid >> 6;                       // 0..3
  const int Nt = bid & 63;                       // 0..63
  const int t = threadIdx.x, lane = t & 63, w = t >> 6;
  const int wr = w >> 1, wc = w & 1, ql = lane & 15, g = lane >> 4;
  const f4 fzero = {0.f, 0.f, 0.f, 0.f};

  // ---- phase 1: KP
  {
    f4 acc[4][4];
#pragma unroll
    for (int i = 0; i < 4; ++i)
#pragma unroll
      for (int j = 0; j < 4; ++j) acc[i][j] = fzero;
    const u16* Ab = wh + (size_t)(Mt * 256) * 1024;
    const u16* Bb = xh + (size_t)(Nt * 128) * 1024;
    gemm_core<16>(Ab, 1024, Bb, 1024, lA, lB, t, wr, wc, ql, g, acc);
#pragma unroll
    for (int rt = 0; rt < 4; ++rt) {
#pragma unroll
      for (int ct = 0; ct < 4; ++ct) {
        f4 v = acc[rt][ct];
        int f = Mt * 256 + wr * 64 + rt * 16 + g * 4;
        int s = Nt * 128 + wc * 64 + ct * 16 + ql;
        ushort4 hh;
        hh.x = f2bf(v[0]); hh.y = f2bf(v[1]); hh.z = f2bf(v[2]); hh.w = f2bf(v[3]);
        if (f < 512) *(ushort4*)&kh[(size_t)s * 512 + f] = hh;
        else         *(ushort4*)&ph[(size_t)s * 512 + (f - 512)] = hh;
      }
    }
  }
  __syncthreads();
  // ---- phase 2: U sub-tile 128s x 128d, simple 2-phase, per-wave 64x32.
  {
    const int wr2 = w >> 2, wc2 = w & 3;   // A 64-row half, B 32-col slice
    f4 acc2[4][2];
#pragma unroll
    for (int i = 0; i < 4; ++i)
#pragma unroll
      for (int j = 0; j < 2; ++j) acc2[i][j] = fzero;
    const u16* Ua = xh + (size_t)(Nt * 128) * 1024;          // x s-rows
    const u16* Ub = wh + (size_t)(1024 + Mt * 128) * 1024;   // Wu d-rows
    u16* uA = lB;          // [2][8192]
    u16* uB = lA;          // first [2][8192] of lA
    stageB128(Ua, 1024, uA, t);
    stageB128(Ub, 1024, uB, t);
    asm volatile("s_waitcnt vmcnt(0)" ::: "memory");
    __builtin_amdgcn_s_barrier();
    asm volatile("" ::: "memory");
    for (int j = 0; j < 16; ++j) {
      const int buf = j & 1;
      if (j + 1 < 16) {
        stageB128(Ua + (j + 1) * 64, 1024, uA + (buf ^ 1) * 8192, t);
        stageB128(Ub + (j + 1) * 64, 1024, uB + (buf ^ 1) * 8192, t);
      }
#pragma unroll
      for (int kk = 0; kk < 2; ++kk) {
        b16x8 af[4], bf[2];
#pragma unroll
        for (int rt = 0; rt < 4; ++rt)
          af[rt] = readfrag(uA + buf * 8192, wr2 * 64 + rt * 16 + ql, kk, g);
#pragma unroll
        for (int ct = 0; ct < 2; ++ct)
          bf[ct] = readfrag(uB + buf * 8192, wc2 * 32 + ct * 16 + ql, kk, g);
        __builtin_amdgcn_s_setprio(1);
#pragma unroll
        for (int rt = 0; rt < 4; ++rt)
#pragma unroll
          for (int ct = 0; ct < 2; ++ct)
            acc2[rt][ct] = mfma_(af[rt], bf[ct], acc2[rt][ct]);
        __builtin_amdgcn_s_setprio(0);
      }
      asm volatile("s_waitcnt vmcnt(0)" ::: "memory");
      __builtin_amdgcn_s_barrier();
      asm volatile("" ::: "memory");
    }
    // epilogue: C[s][d], f4 over 4 consecutive s -> ut[b][d][k] ushort4
#pragma unroll
    for (int rt = 0; rt < 4; ++rt) {
#pragma unroll
      for (int ct = 0; ct < 2; ++ct) {
        f4 v = acc2[rt][ct];
        int s = Nt * 128 + wr2 * 64 + rt * 16 + g * 4;
        int d = Mt * 128 + wc2 * 32 + ct * 16 + ql;
        int bb = s >> 11, k0 = s & 2047;
        ushort4 hh;
        hh.x = f2bf(v[0]); hh.y = f2bf(v[1]); hh.z = f2bf(v[2]); hh.w = f2bf(v[3]);
        *(ushort4*)&ut[((size_t)bb * 512 + d) * 2048 + k0] = hh;
      }
    }
  }
}

// ---------------------------------------------------------------------------
// K3: score GEMM, r17: ONE round of 256 blocks, 256k x 256q, BK=64, simple
// 2-phase, per-wave 128x64 (acc[8][4]). A=K-rows, B=P-rows -> C[k][q].
__global__ __launch_bounds__(512, 1) void k_score(
    const u16* __restrict__ ph, const u16* __restrict__ kh,
    u16* __restrict__ probs, float* __restrict__ l) {
  constexpr float INVT = 0.04419417382415922f;  // 1/sqrt(512)
  __shared__ u16 lK[2][16384], lP[2][16384];    // 128 KB
  const int bid = blockIdx.x;
  const int b = bid >> 6, rem = bid & 63;
  const int Mt = rem >> 3, Nt = rem & 7;        // k-tile, q-tile (256 each)
  const int k0b = Mt * 256, q0b = Nt * 256;
  const int t = threadIdx.x, lane = t & 63, w = t >> 6;
  const int wr = w >> 2, wc = w & 3, ql = lane & 15, g = lane >> 4;
  const f4 fzero = {0.f, 0.f, 0.f, 0.f};
  f4 acc[8][4];
#pragma unroll
  for (int i = 0; i < 8; ++i)
#pragma unroll
    for (int j = 0; j < 4; ++j) acc[i][j] = fzero;

  const u16* Ab = &kh[((size_t)b * 2048 + k0b) * 512];
  const u16* Bb = &ph[((size_t)b * 2048 + q0b) * 512];
  stageA256(Ab, 512, lK[0], t);
  stageA256(Bb, 512, lP[0], t);
  asm volatile("s_waitcnt vmcnt(0)" ::: "memory");
  __builtin_amdgcn_s_barrier();
  asm volatile("" ::: "memory");
  for (int j = 0; j < 8; ++j) {                 // K = 512
    const int buf = j & 1;
    if (j + 1 < 8) {
      stageA256(Ab + (j + 1) * 64, 512, lK[buf ^ 1], t);
      stageA256(Bb + (j + 1) * 64, 512, lP[buf ^ 1], t);
    }
#pragma unroll
    for (int kk = 0; kk < 2; ++kk) {
      b16x8 af[8], bf[4];
#pragma unroll
      for (int rt = 0; rt < 8; ++rt)
        af[rt] = readfrag(lK[buf], wr * 128 + rt * 16 + ql, kk, g);
#pragma unroll
      for (int ct = 0; ct < 4; ++ct)
        bf[ct] = readfrag(lP[buf], wc * 64 + ct * 16 + ql, kk, g);
      __builtin_amdgcn_s_setprio(1);
#pragma unroll
      for (int rt = 0; rt < 8; ++rt)
#pragma unroll
        for (int ct = 0; ct < 4; ++ct)
          acc[rt][ct] = mfma_(af[rt], bf[ct], acc[rt][ct]);
      __builtin_amdgcn_s_setprio(0);
    }
    asm volatile("s_waitcnt vmcnt(0)" ::: "memory");
    __builtin_amdgcn_s_barrier();
    asm volatile("" ::: "memory");
  }

  float lq[4] = {0.f, 0.f, 0.f, 0.f};
#pragma unroll
  for (int rt = 0; rt < 8; ++rt) {
    int kr = k0b + wr * 128 + rt * 16 + g * 4;
#pragma unroll
    for (int ct = 0; ct < 4; ++ct) {
      int q = q0b + wc * 64 + ct * 16 + ql;
      f4 a = acc[rt][ct];
      float p0 = __expf(a[0] * INVT), p1 = __expf(a[1] * INVT);
      float p2 = __expf(a[2] * INVT), p3 = __expf(a[3] * INVT);
      ushort4 hh;
      hh.x = f2bf(p0); hh.y = f2bf(p1); hh.z = f2bf(p2); hh.w = f2bf(p3);
      *(ushort4*)&probs[((size_t)b * 2048 + q) * 2048 + kr] = hh;
      lq[ct] += (p0 + p1) + (p2 + p3);
    }
  }
#pragma unroll
  for (int ct = 0; ct < 4; ++ct) {
    float s = lq[ct];
    s += __shfl_xor(s, 16);
    s += __shfl_xor(s, 32);
    if (lane < 16) atomicAdd(&l[b * 2048 + q0b + wc * 64 + ct * 16 + lane], s);
  }
}

// ---------------------------------------------------------------------------
// K4: output GEMM (unchanged r16 split-K). Grid 256, 512 thr.
__global__ __launch_bounds__(512, 1) void k_out(
    const u16* __restrict__ ut, const u16* __restrict__ probs,
    const float* __restrict__ l, float* __restrict__ out) {
  __shared__ u16 buf[65536];                     // 128 KB
  const int bid = blockIdx.x;
  const int b = bid >> 6, rem = bid & 63;
  const int Mt = rem >> 4, Nt = rem & 15;
  const int d0 = Mt * 128, q0 = Nt * 128;
  const int t = threadIdx.x;
  const int grp = t >> 8, tl = t & 255;
  const int lane = tl & 63, w = tl >> 6;
  const int wr = w >> 1, wc = w & 1, ql = lane & 15, g = lane >> 4;
  const f4 fzero = {0.f, 0.f, 0.f, 0.f};
  f4 acc[4][4];
#pragma unroll
  for (int i = 0; i < 4; ++i)
#pragma unroll
    for (int j = 0; j < 4; ++j) acc[i][j] = fzero;

  u16* myA = buf + grp * 32768;
  u16* myB = buf + grp * 32768 + 16384;
  const u16* Ab = &ut[((size_t)b * 512 + d0) * 2048 + grp * 1024];
  const u16* Bb = &probs[((size_t)b * 2048 + q0) * 2048 + grp * 1024];
  gemm_core128<16>(Ab, 2048, Bb, 2048, myA, myB, tl, wr, wc, ql, g, acc);

  __syncthreads();
  float* red = (float*)buf;
  if (grp == 1) {
#pragma unroll
    for (int rt = 0; rt < 4; ++rt)
#pragma unroll
      for (int ct = 0; ct < 4; ++ct) {
        int dl = wr * 64 + rt * 16 + g * 4;
        int qlq = wc * 64 + ct * 16 + ql;
#pragma unroll
        for (int r = 0; r < 4; ++r) red[(dl + r) * 128 + qlq] = acc[rt][ct][r];
      }
  }
  __syncthreads();
  if (grp == 0) {
#pragma unroll
    for (int ct = 0; ct < 4; ++ct) {
      int qlq = wc * 64 + ct * 16 + ql;
      int q = q0 + qlq;
      float inv = 1.0f / l[b * 2048 + q];
      size_t orow = ((size_t)b * 2048 + q) * 512;
#pragma unroll
      for (int rt = 0; rt < 4; ++rt) {
        int dl = wr * 64 + rt * 16 + g * 4;
        f4 v;
#pragma unroll
        for (int r = 0; r < 4; ++r) v[r] = acc[rt][ct][r] + red[(dl + r) * 128 + qlq];
        v *= inv;
        *(f4*)&out[orow + d0 + dl] = v;
      }
    }
  }
}

// ---------------------------------------------------------------------------
extern "C" void kernel_launch(void* const* d_in, const int* in_sizes, int n_in,
                              void* d_out, int out_size, void* d_ws, size_t ws_size,
                              hipStream_t stream) {
  const float* x = (const float*)d_in[0];
  const float* Wk = (const float*)d_in[1];
  const float* Wq = (const float*)d_in[2];
  const float* Wv = (const float*)d_in[3];
  const float* Wa = (const float*)d_in[4];
  const float* Wb = (const float*)d_in[5];
  float* out = (float*)d_out;

  char* ws = (char*)d_ws;
  size_t off = 0;
  auto alloc = [&](size_t bytes) -> void* {
    void* p = ws + off;
    off += (bytes + 255) & ~(size_t)255;
    return p;
  };
  u16* wh = (u16*)alloc((size_t)1536 * 1024 * 2);
  u16* xh = (u16*)alloc((size_t)8192 * 1024 * 2);
  u16* kh = (u16*)alloc((size_t)8192 * 512 * 2);
  u16* ph = (u16*)alloc((size_t)8192 * 512 * 2);
  u16* ut = (u16*)alloc((size_t)8192 * 512 * 2);
  u16* probs = (u16*)alloc((size_t)4 * 2048 * 2048 * 2);
  float* l = (float*)alloc(8192 * 4);
  u16* waT_h = (u16*)alloc((size_t)512 * 512 * 2);
  u16* waT_l = (u16*)alloc((size_t)512 * 512 * 2);
  u16* wqT_h = (u16*)alloc((size_t)1024 * 512 * 2);
  u16* wqT_l = (u16*)alloc((size_t)1024 * 512 * 2);
  u16* wb_h = (u16*)alloc((size_t)512 * 512 * 2);
  u16* wb_l = (u16*)alloc((size_t)512 * 512 * 2);
  u16* wvT_h = (u16*)alloc((size_t)1024 * 512 * 2);
  u16* wvT_l = (u16*)alloc((size_t)1024 * 512 * 2);
  (void)ws_size; (void)in_sizes; (void)n_in; (void)out_size;

  hipLaunchKernelGGL(k_prep_w, dim3(1096), dim3(256), 0, stream,
                     Wk, Wq, Wv, Wa, Wb, wh,
                     waT_h, waT_l, wqT_h, wqT_l, wb_h, wb_l, wvT_h, wvT_l, l);
  hipLaunchKernelGGL(k_fx, dim3(8256), dim3(256), 0, stream,
                     x, waT_h, waT_l, wqT_h, wqT_l, wb_h, wb_l, wvT_h, wvT_l,
                     xh, wh);
  hipLaunchKernelGGL(k_proj, dim3(256), dim3(512), 0, stream, xh, wh, kh, ph, ut);
  hipLaunchKernelGGL(k_score, dim3(256), dim3(512), 0, stream, ph, kh, probs, l);
  hipLaunchKernelGGL(k_out, dim3(256), dim3(512), 0, stream, ut, probs, l, out);
}

// Round 18
// 111.100 us; speedup vs baseline: 1.2954x; 1.0333x over previous
//
#include <hip/hip_runtime.h>

// SelfAttention_33852932227207 — MI355X, round 18.
// e = x^T (Wq^T Wa Wk) x / sqrt(512);  out = softmax(e) @ (x (Wb Wv)^T).
// r18: XCD-aware block swizzles only (T1). r17 k_proj FETCH=49.8MB vs ~20MB
// unique (2.5x over-fetch): round-robin XCD placement makes every XCD
// re-fetch panels its neighbors hold. New mapping pins each XCD to a
// contiguous tile slab (k_proj: all Mt x 8 Nt; k_score: (b,Mt) slab;
// k_out: (b,Mt,Nt) slab). Pure index permutation -> bit-identical output.
// All kernels otherwise byte-identical to r17.

typedef __attribute__((ext_vector_type(8))) short b16x8;
typedef __attribute__((ext_vector_type(4))) float f4;
typedef unsigned short u16;

#define DEVINL __device__ __forceinline__

DEVINL u16 f2bf(float f) {               // fp32 -> bf16 RNE
  unsigned int u = __float_as_uint(f);
  u = u + 0x7FFFu + ((u >> 16) & 1u);
  return (u16)(u >> 16);
}
DEVINL float bf2f(u16 h) { return __uint_as_float(((unsigned int)h) << 16); }

DEVINL f4 mfma_(b16x8 a, b16x8 b, f4 c) {
  return __builtin_amdgcn_mfma_f32_16x16x32_bf16(a, b, c, 0, 0, 0);
}
// bf16x3: (ah+al)*(bh+bl) ~= ah*bh + ah*bl + al*bh
DEVINL f4 mfma3(b16x8 ah, b16x8 al, b16x8 bh, b16x8 bl, f4 c) {
  c = mfma_(ah, bh, c);
  c = mfma_(ah, bl, c);
  c = mfma_(al, bh, c);
  return c;
}
DEVINL void gload16(const u16* g, u16* l) {
  __builtin_amdgcn_global_load_lds(
      (const __attribute__((address_space(1))) void*)g,
      (__attribute__((address_space(3))) void*)l, 16, 0, 0);
}

// ---- 16B-chunk XOR swizzle tile helpers (r5-proven, bank-conflict=0).
DEVINL void stage_tile(const u16* __restrict__ gbase, int rstride,
                       u16* __restrict__ lds, int t) {      // 128x64, 256 thr
#pragma unroll
  for (int r = 0; r < 4; ++r) {
    int cp = r * 256 + t;
    int row = cp >> 3, j = cp & 7;
    int jj = j ^ (row & 7);
    gload16(&gbase[(size_t)row * rstride + jj * 8], &lds[cp * 8]);
  }
}
DEVINL void stageA256(const u16* __restrict__ gbase, int rstride,
                      u16* __restrict__ lds, int t) {       // 256x64, 512 thr
#pragma unroll
  for (int r = 0; r < 4; ++r) {
    int cp = r * 512 + t;                // 2048 chunks
    int row = cp >> 3, j = cp & 7;
    int jj = j ^ (row & 7);
    gload16(&gbase[(size_t)row * rstride + jj * 8], &lds[cp * 8]);
  }
}
DEVINL void stageB128(const u16* __restrict__ gbase, int rstride,
                      u16* __restrict__ lds, int t) {       // 128x64, 512 thr
#pragma unroll
  for (int r = 0; r < 2; ++r) {
    int cp = r * 512 + t;                // 1024 chunks
    int row = cp >> 3, j = cp & 7;
    int jj = j ^ (row & 7);
    gload16(&gbase[(size_t)row * rstride + jj * 8], &lds[cp * 8]);
  }
}
DEVINL b16x8 readfrag(const u16* __restrict__ lds, int row, int kk, int g) {
  int chunk = row * 8 + ((kk * 4 + g) ^ (row & 7));
  return *(const b16x8*)&lds[chunk * 8];
}

// ---- r13 core: 256x128 BK=64 8-wave, reads-one-half-ahead.
template <int NT>
DEVINL void gemm_core(const u16* __restrict__ Ab, int sA,
                      const u16* __restrict__ Bb, int sB,
                      u16* __restrict__ ldsA, u16* __restrict__ ldsB,
                      int t, int wr, int wc, int ql, int g, f4 acc[4][4]) {
  b16x8 fa[4], fb[4];
  b16x8 ga[4], gb[4];
  stageA256(Ab, sA, ldsA, t);
  stageB128(Bb, sB, ldsB, t);
  stageA256(Ab + 64, sA, ldsA + 16384, t);
  stageB128(Bb + 64, sB, ldsB + 8192, t);
  asm volatile("s_waitcnt vmcnt(6)" ::: "memory");
  __builtin_amdgcn_s_barrier();
  asm volatile("" ::: "memory");
  u16 *cA = ldsA, *cB = ldsB, *nA = ldsA + 16384, *nB = ldsB + 8192;
#pragma unroll
  for (int i = 0; i < 4; ++i) {
    fa[i] = readfrag(cA, wr * 64 + i * 16 + ql, 0, g);
    fb[i] = readfrag(cB, wc * 64 + i * 16 + ql, 0, g);
  }
  for (int j = 0; j < NT; ++j) {
#pragma unroll
    for (int i = 0; i < 4; ++i) {
      ga[i] = readfrag(cA, wr * 64 + i * 16 + ql, 1, g);
      gb[i] = readfrag(cB, wc * 64 + i * 16 + ql, 1, g);
    }
    __builtin_amdgcn_s_setprio(1);
#pragma unroll
    for (int rt = 0; rt < 4; ++rt)
#pragma unroll
      for (int ct = 0; ct < 4; ++ct)
        acc[rt][ct] = mfma_(fa[rt], fb[ct], acc[rt][ct]);
    __builtin_amdgcn_s_setprio(0);
    asm volatile("s_waitcnt vmcnt(0)" ::: "memory");
    __builtin_amdgcn_s_barrier();
    asm volatile("" ::: "memory");
    if (j + 1 < NT) {
#pragma unroll
      for (int i = 0; i < 4; ++i) {
        fa[i] = readfrag(nA, wr * 64 + i * 16 + ql, 0, g);
        fb[i] = readfrag(nB, wc * 64 + i * 16 + ql, 0, g);
      }
    }
    if (j + 2 < NT) {
      stageA256(Ab + (j + 2) * 64, sA, cA, t);
      stageB128(Bb + (j + 2) * 64, sB, cB, t);
    }
    __builtin_amdgcn_s_setprio(1);
#pragma unroll
    for (int rt = 0; rt < 4; ++rt)
#pragma unroll
      for (int ct = 0; ct < 4; ++ct)
        acc[rt][ct] = mfma_(ga[rt], gb[ct], acc[rt][ct]);
    __builtin_amdgcn_s_setprio(0);
    u16* tmp = cA; cA = nA; nA = tmp;
    tmp = cB; cB = nB; nB = tmp;
  }
}

// ---- r15 core: 128x128 BK=64, 4-wave group (256 thr), k_out split-K.
template <int NT>
DEVINL void gemm_core128(const u16* __restrict__ Ab, int sA,
                         const u16* __restrict__ Bb, int sB,
                         u16* __restrict__ ldsA, u16* __restrict__ ldsB,
                         int t, int wr, int wc, int ql, int g, f4 acc[4][4]) {
  b16x8 fa[4], fb[4];
  b16x8 ga[4], gb[4];
  stage_tile(Ab, sA, ldsA, t);
  stage_tile(Bb, sB, ldsB, t);
  stage_tile(Ab + 64, sA, ldsA + 8192, t);
  stage_tile(Bb + 64, sB, ldsB + 8192, t);
  asm volatile("s_waitcnt vmcnt(8)" ::: "memory");
  __builtin_amdgcn_s_barrier();
  asm volatile("" ::: "memory");
  u16 *cA = ldsA, *cB = ldsB, *nA = ldsA + 8192, *nB = ldsB + 8192;
#pragma unroll
  for (int i = 0; i < 4; ++i) {
    fa[i] = readfrag(cA, wr * 64 + i * 16 + ql, 0, g);
    fb[i] = readfrag(cB, wc * 64 + i * 16 + ql, 0, g);
  }
  for (int j = 0; j < NT; ++j) {
#pragma unroll
    for (int i = 0; i < 4; ++i) {
      ga[i] = readfrag(cA, wr * 64 + i * 16 + ql, 1, g);
      gb[i] = readfrag(cB, wc * 64 + i * 16 + ql, 1, g);
    }
    __builtin_amdgcn_s_setprio(1);
#pragma unroll
    for (int rt = 0; rt < 4; ++rt)
#pragma unroll
      for (int ct = 0; ct < 4; ++ct)
        acc[rt][ct] = mfma_(fa[rt], fb[ct], acc[rt][ct]);
    __builtin_amdgcn_s_setprio(0);
    asm volatile("s_waitcnt vmcnt(0)" ::: "memory");
    __builtin_amdgcn_s_barrier();
    asm volatile("" ::: "memory");
    if (j + 1 < NT) {
#pragma unroll
      for (int i = 0; i < 4; ++i) {
        fa[i] = readfrag(nA, wr * 64 + i * 16 + ql, 0, g);
        fb[i] = readfrag(nB, wc * 64 + i * 16 + ql, 0, g);
      }
    }
    if (j + 2 < NT) {
      stage_tile(Ab + (j + 2) * 64, sA, cA, t);
      stage_tile(Bb + (j + 2) * 64, sB, cB, t);
    }
    __builtin_amdgcn_s_setprio(1);
#pragma unroll
    for (int rt = 0; rt < 4; ++rt)
#pragma unroll
      for (int ct = 0; ct < 4; ++ct)
        acc[rt][ct] = mfma_(ga[rt], gb[ct], acc[rt][ct]);
    __builtin_amdgcn_s_setprio(0);
    u16* tmp = cA; cA = nA; nA = tmp;
    tmp = cB; cB = nB; nB = tmp;
  }
}

// ---------------------------------------------------------------------------
// K0: weight prep + l zero (unchanged r16). Grid 1096.
__global__ __launch_bounds__(256) void k_prep_w(
    const float* __restrict__ Wk, const float* __restrict__ Wq,
    const float* __restrict__ Wv, const float* __restrict__ Wa,
    const float* __restrict__ Wb, u16* __restrict__ wh,
    u16* __restrict__ waT_h, u16* __restrict__ waT_l,
    u16* __restrict__ wqT_h, u16* __restrict__ wqT_l,
    u16* __restrict__ wb_h, u16* __restrict__ wb_l,
    u16* __restrict__ wvT_h, u16* __restrict__ wvT_l,
    float* __restrict__ l) {
  const int bid = blockIdx.x, t = threadIdx.x;
  if (bid < 512) {
    int i = bid * 256 + t;
    float4 v = ((const float4*)Wk)[i];
    ushort4 h;
    h.x = f2bf(v.x); h.y = f2bf(v.y); h.z = f2bf(v.z); h.w = f2bf(v.w);
    ((ushort4*)wh)[i] = h;
    return;
  }
  if (bid < 768) {
    int i = (bid - 512) * 256 + t;
    float4 v = ((const float4*)Wb)[i];
    ushort4 h, lo;
    h.x = f2bf(v.x); lo.x = f2bf(v.x - bf2f(h.x));
    h.y = f2bf(v.y); lo.y = f2bf(v.y - bf2f(h.y));
    h.z = f2bf(v.z); lo.z = f2bf(v.z - bf2f(h.z));
    h.w = f2bf(v.w); lo.w = f2bf(v.w - bf2f(h.w));
    ((ushort4*)wb_h)[i] = h;
    ((ushort4*)wb_l)[i] = lo;
    return;
  }
  if (bid >= 1088) {
    int i = (bid - 1088) * 256 + t;
    float4 z = {0.f, 0.f, 0.f, 0.f};
    ((float4*)l)[i] = z;
    return;
  }
  __shared__ float ftile[64][68];
  const int tb = bid - 768;
  const float* src;
  u16 *dh, *dl;
  int S, m0, c0;
  if (tb < 64) {
    src = Wa; dh = waT_h; dl = waT_l; S = 512;
    m0 = (tb >> 3) * 64; c0 = (tb & 7) * 64;
  } else if (tb < 192) {
    int q = tb - 64;
    src = Wq; dh = wqT_h; dl = wqT_l; S = 1024;
    m0 = (q >> 4) * 64; c0 = (q & 15) * 64;
  } else {
    int q = tb - 192;
    src = Wv; dh = wvT_h; dl = wvT_l; S = 1024;
    m0 = (q >> 4) * 64; c0 = (q & 15) * 64;
  }
  {
    int i = t >> 4, j4 = (t & 15) * 4;
#pragma unroll
    for (int ii = 0; ii < 4; ++ii) {
      int row = i + ii * 16;
      float4 v = *(const float4*)&src[(size_t)(m0 + row) * S + c0 + j4];
      ftile[row][j4] = v.x; ftile[row][j4 + 1] = v.y;
      ftile[row][j4 + 2] = v.z; ftile[row][j4 + 3] = v.w;
    }
  }
  __syncthreads();
  {
    int oc = t >> 2, mc = (t & 3) * 16;
#pragma unroll
    for (int j = 0; j < 4; ++j) {
      int m = mc + j * 4;
      float v0 = ftile[m][oc], v1 = ftile[m + 1][oc];
      float v2 = ftile[m + 2][oc], v3 = ftile[m + 3][oc];
      ushort4 h, lo;
      h.x = f2bf(v0); lo.x = f2bf(v0 - bf2f(h.x));
      h.y = f2bf(v1); lo.y = f2bf(v1 - bf2f(h.y));
      h.z = f2bf(v2); lo.z = f2bf(v2 - bf2f(h.z));
      h.w = f2bf(v3); lo.w = f2bf(v3 - bf2f(h.w));
      size_t o = (size_t)(c0 + oc) * 512 + m0 + m;
      *(ushort4*)&dh[o] = h;
      *(ushort4*)&dl[o] = lo;
    }
  }
}

// ---------------------------------------------------------------------------
// K1: fused fold + x-conversion (unchanged r16). Grid 8256.
__global__ __launch_bounds__(256) void k_fx(
    const float* __restrict__ x,
    const u16* __restrict__ waT_h, const u16* __restrict__ waT_l,
    const u16* __restrict__ wqT_h, const u16* __restrict__ wqT_l,
    const u16* __restrict__ wb_h, const u16* __restrict__ wb_l,
    const u16* __restrict__ wvT_h, const u16* __restrict__ wvT_l,
    u16* __restrict__ xh, u16* __restrict__ wh) {
  const int bid = blockIdx.x, t = threadIdx.x;
  if (bid >= 64) {                       // x conversion
    int i = (bid - 64) * 256 + t;
    float4 v = ((const float4*)x)[i];
    ushort4 h;
    h.x = f2bf(v.x); h.y = f2bf(v.y); h.z = f2bf(v.z); h.w = f2bf(v.w);
    ((ushort4*)xh)[i] = h;
    return;
  }
  __shared__ u16 lah[8192], lal[8192], lbh[8192], lbl[8192];
  const int which = bid >> 5;
  const int idx = bid & 31;
  const int r0 = (idx >> 3) * 128, c0 = (idx & 7) * 128;
  const u16* Ah = which ? wb_h : waT_h;
  const u16* Al = which ? wb_l : waT_l;
  const u16* Bh = which ? wvT_h : wqT_h;
  const u16* Bl = which ? wvT_l : wqT_l;
  const int obase = which ? 1024 : 512;
  const int lane = t & 63, w = t >> 6;
  const int wr = w >> 1, wc = w & 1, ql = lane & 15, g = lane >> 4;
  const f4 fzero = {0.f, 0.f, 0.f, 0.f};
  f4 acc[4][4];
#pragma unroll
  for (int i = 0; i < 4; ++i)
#pragma unroll
    for (int j = 0; j < 4; ++j) acc[i][j] = fzero;

  for (int ks = 0; ks < 8; ++ks) {
    __syncthreads();
    stage_tile(&Ah[(size_t)r0 * 512 + ks * 64], 512, lah, t);
    stage_tile(&Al[(size_t)r0 * 512 + ks * 64], 512, lal, t);
    stage_tile(&Bh[(size_t)c0 * 512 + ks * 64], 512, lbh, t);
    stage_tile(&Bl[(size_t)c0 * 512 + ks * 64], 512, lbl, t);
    __syncthreads();
#pragma unroll
    for (int kk = 0; kk < 2; ++kk) {
      b16x8 ah[4], al[4], bh[4], bl[4];
#pragma unroll
      for (int rt = 0; rt < 4; ++rt) {
        ah[rt] = readfrag(lah, wr * 64 + rt * 16 + ql, kk, g);
        al[rt] = readfrag(lal, wr * 64 + rt * 16 + ql, kk, g);
      }
#pragma unroll
      for (int ct = 0; ct < 4; ++ct) {
        bh[ct] = readfrag(lbh, wc * 64 + ct * 16 + ql, kk, g);
        bl[ct] = readfrag(lbl, wc * 64 + ct * 16 + ql, kk, g);
      }
#pragma unroll
      for (int rt = 0; rt < 4; ++rt)
#pragma unroll
        for (int ct = 0; ct < 4; ++ct)
          acc[rt][ct] = mfma3(ah[rt], al[rt], bh[ct], bl[ct], acc[rt][ct]);
    }
  }
#pragma unroll
  for (int rt = 0; rt < 4; ++rt) {
#pragma unroll
    for (int ct = 0; ct < 4; ++ct) {
      f4 v = acc[rt][ct];
      int col = c0 + wc * 64 + ct * 16 + ql;
      int rowb = r0 + wr * 64 + rt * 16 + g * 4;
#pragma unroll
      for (int r = 0; r < 4; ++r)
        wh[(size_t)(obase + rowb + r) * 1024 + col] = f2bf(v[r]);
    }
  }
}

// ---------------------------------------------------------------------------
// K2: projection GEMM (r17 structure; r18 XCD-pinned mapping).
// XCD x owns {Mt 0..3} x {Nt x*8..x*8+7}: per-XCD set = wh 3MB + 8 x-panels.
__global__ __launch_bounds__(512, 1) void k_proj(
    const u16* __restrict__ xh, const u16* __restrict__ wh,
    u16* __restrict__ kh, u16* __restrict__ ph, u16* __restrict__ ut) {
  __shared__ u16 lA[2 * 16384], lB[2 * 8192];    // 96 KB
  const int bid = blockIdx.x;
  const int xcd = bid & 7, slot = bid >> 3;      // slot 0..31
  const int Mt = slot >> 3;                      // 0..3
  const int Nt = xcd * 8 + (slot & 7);           // 0..63 (bijective)
  const int t = threadIdx.x, lane = t & 63, w = t >> 6;
  const int wr = w >> 1, wc = w & 1, ql = lane & 15, g = lane >> 4;
  const f4 fzero = {0.f, 0.f, 0.f, 0.f};

  // ---- phase 1: KP
  {
    f4 acc[4][4];
#pragma unroll
    for (int i = 0; i < 4; ++i)
#pragma unroll
      for (int j = 0; j < 4; ++j) acc[i][j] = fzero;
    const u16* Ab = wh + (size_t)(Mt * 256) * 1024;
    const u16* Bb = xh + (size_t)(Nt * 128) * 1024;
    gemm_core<16>(Ab, 1024, Bb, 1024, lA, lB, t, wr, wc, ql, g, acc);
#pragma unroll
    for (int rt = 0; rt < 4; ++rt) {
#pragma unroll
      for (int ct = 0; ct < 4; ++ct) {
        f4 v = acc[rt][ct];
        int f = Mt * 256 + wr * 64 + rt * 16 + g * 4;
        int s = Nt * 128 + wc * 64 + ct * 16 + ql;
        ushort4 hh;
        hh.x = f2bf(v[0]); hh.y = f2bf(v[1]); hh.z = f2bf(v[2]); hh.w = f2bf(v[3]);
        if (f < 512) *(ushort4*)&kh[(size_t)s * 512 + f] = hh;
        else         *(ushort4*)&ph[(size_t)s * 512 + (f - 512)] = hh;
      }
    }
  }
  __syncthreads();
  // ---- phase 2: U sub-tile 128s x 128d, simple 2-phase, per-wave 64x32.
  {
    const int wr2 = w >> 2, wc2 = w & 3;
    f4 acc2[4][2];
#pragma unroll
    for (int i = 0; i < 4; ++i)
#pragma unroll
      for (int j = 0; j < 2; ++j) acc2[i][j] = fzero;
    const u16* Ua = xh + (size_t)(Nt * 128) * 1024;
    const u16* Ub = wh + (size_t)(1024 + Mt * 128) * 1024;
    u16* uA = lB;
    u16* uB = lA;
    stageB128(Ua, 1024, uA, t);
    stageB128(Ub, 1024, uB, t);
    asm volatile("s_waitcnt vmcnt(0)" ::: "memory");
    __builtin_amdgcn_s_barrier();
    asm volatile("" ::: "memory");
    for (int j = 0; j < 16; ++j) {
      const int buf = j & 1;
      if (j + 1 < 16) {
        stageB128(Ua + (j + 1) * 64, 1024, uA + (buf ^ 1) * 8192, t);
        stageB128(Ub + (j + 1) * 64, 1024, uB + (buf ^ 1) * 8192, t);
      }
#pragma unroll
      for (int kk = 0; kk < 2; ++kk) {
        b16x8 af[4], bf[2];
#pragma unroll
        for (int rt = 0; rt < 4; ++rt)
          af[rt] = readfrag(uA + buf * 8192, wr2 * 64 + rt * 16 + ql, kk, g);
#pragma unroll
        for (int ct = 0; ct < 2; ++ct)
          bf[ct] = readfrag(uB + buf * 8192, wc2 * 32 + ct * 16 + ql, kk, g);
        __builtin_amdgcn_s_setprio(1);
#pragma unroll
        for (int rt = 0; rt < 4; ++rt)
#pragma unroll
          for (int ct = 0; ct < 2; ++ct)
            acc2[rt][ct] = mfma_(af[rt], bf[ct], acc2[rt][ct]);
        __builtin_amdgcn_s_setprio(0);
      }
      asm volatile("s_waitcnt vmcnt(0)" ::: "memory");
      __builtin_amdgcn_s_barrier();
      asm volatile("" ::: "memory");
    }
#pragma unroll
    for (int rt = 0; rt < 4; ++rt) {
#pragma unroll
      for (int ct = 0; ct < 2; ++ct) {
        f4 v = acc2[rt][ct];
        int s = Nt * 128 + wr2 * 64 + rt * 16 + g * 4;
        int d = Mt * 128 + wc2 * 32 + ct * 16 + ql;
        int bb = s >> 11, k0 = s & 2047;
        ushort4 hh;
        hh.x = f2bf(v[0]); hh.y = f2bf(v[1]); hh.z = f2bf(v[2]); hh.w = f2bf(v[3]);
        *(ushort4*)&ut[((size_t)bb * 512 + d) * 2048 + k0] = hh;
      }
    }
  }
}

// ---------------------------------------------------------------------------
// K3: score GEMM (r17 structure; r18 XCD-pinned mapping).
// XCD x owns a contiguous (b,Mt) slab: per-XCD K-panels + P full-batch reuse.
__global__ __launch_bounds__(512, 1) void k_score(
    const u16* __restrict__ ph, const u16* __restrict__ kh,
    u16* __restrict__ probs, float* __restrict__ l) {
  constexpr float INVT = 0.04419417382415922f;  // 1/sqrt(512)
  __shared__ u16 lK[2][16384], lP[2][16384];    // 128 KB
  const int bid = blockIdx.x;
  const int xcd = bid & 7, slot = bid >> 3;     // slot 0..31
  const int lin = xcd * 32 + slot;              // 0..255, XCD-contiguous
  const int b = lin >> 6, rem = lin & 63;
  const int Mt = rem >> 3, Nt = rem & 7;        // k-tile, q-tile (256 each)
  const int k0b = Mt * 256, q0b = Nt * 256;
  const int t = threadIdx.x, lane = t & 63, w = t >> 6;
  const int wr = w >> 2, wc = w & 3, ql = lane & 15, g = lane >> 4;
  const f4 fzero = {0.f, 0.f, 0.f, 0.f};
  f4 acc[8][4];
#pragma unroll
  for (int i = 0; i < 8; ++i)
#pragma unroll
    for (int j = 0; j < 4; ++j) acc[i][j] = fzero;

  const u16* Ab = &kh[((size_t)b * 2048 + k0b) * 512];
  const u16* Bb = &ph[((size_t)b * 2048 + q0b) * 512];
  stageA256(Ab, 512, lK[0], t);
  stageA256(Bb, 512, lP[0], t);
  asm volatile("s_waitcnt vmcnt(0)" ::: "memory");
  __builtin_amdgcn_s_barrier();
  asm volatile("" ::: "memory");
  for (int j = 0; j < 8; ++j) {                 // K = 512
    const int buf = j & 1;
    if (j + 1 < 8) {
      stageA256(Ab + (j + 1) * 64, 512, lK[buf ^ 1], t);
      stageA256(Bb + (j + 1) * 64, 512, lP[buf ^ 1], t);
    }
#pragma unroll
    for (int kk = 0; kk < 2; ++kk) {
      b16x8 af[8], bf[4];
#pragma unroll
      for (int rt = 0; rt < 8; ++rt)
        af[rt] = readfrag(lK[buf], wr * 128 + rt * 16 + ql, kk, g);
#pragma unroll
      for (int ct = 0; ct < 4; ++ct)
        bf[ct] = readfrag(lP[buf], wc * 64 + ct * 16 + ql, kk, g);
      __builtin_amdgcn_s_setprio(1);
#pragma unroll
      for (int rt = 0; rt < 8; ++rt)
#pragma unroll
        for (int ct = 0; ct < 4; ++ct)
          acc[rt][ct] = mfma_(af[rt], bf[ct], acc[rt][ct]);
      __builtin_amdgcn_s_setprio(0);
    }
    asm volatile("s_waitcnt vmcnt(0)" ::: "memory");
    __builtin_amdgcn_s_barrier();
    asm volatile("" ::: "memory");
  }

  float lq[4] = {0.f, 0.f, 0.f, 0.f};
#pragma unroll
  for (int rt = 0; rt < 8; ++rt) {
    int kr = k0b + wr * 128 + rt * 16 + g * 4;
#pragma unroll
    for (int ct = 0; ct < 4; ++ct) {
      int q = q0b + wc * 64 + ct * 16 + ql;
      f4 a = acc[rt][ct];
      float p0 = __expf(a[0] * INVT), p1 = __expf(a[1] * INVT);
      float p2 = __expf(a[2] * INVT), p3 = __expf(a[3] * INVT);
      ushort4 hh;
      hh.x = f2bf(p0); hh.y = f2bf(p1); hh.z = f2bf(p2); hh.w = f2bf(p3);
      *(ushort4*)&probs[((size_t)b * 2048 + q) * 2048 + kr] = hh;
      lq[ct] += (p0 + p1) + (p2 + p3);
    }
  }
#pragma unroll
  for (int ct = 0; ct < 4; ++ct) {
    float s = lq[ct];
    s += __shfl_xor(s, 16);
    s += __shfl_xor(s, 32);
    if (lane < 16) atomicAdd(&l[b * 2048 + q0b + wc * 64 + ct * 16 + lane], s);
  }
}

// ---------------------------------------------------------------------------
// K4: output GEMM (r16 split-K structure; r18 XCD-pinned mapping).
__global__ __launch_bounds__(512, 1) void k_out(
    const u16* __restrict__ ut, const u16* __restrict__ probs,
    const float* __restrict__ l, float* __restrict__ out) {
  __shared__ u16 buf[65536];                     // 128 KB
  const int bid = blockIdx.x;
  const int xcd = bid & 7, slot = bid >> 3;
  const int lin = xcd * 32 + slot;               // 0..255, XCD-contiguous
  const int b = lin >> 6, rem = lin & 63;
  const int Mt = rem >> 4, Nt = rem & 15;
  const int d0 = Mt * 128, q0 = Nt * 128;
  const int t = threadIdx.x;
  const int grp = t >> 8, tl = t & 255;
  const int lane = tl & 63, w = tl >> 6;
  const int wr = w >> 1, wc = w & 1, ql = lane & 15, g = lane >> 4;
  const f4 fzero = {0.f, 0.f, 0.f, 0.f};
  f4 acc[4][4];
#pragma unroll
  for (int i = 0; i < 4; ++i)
#pragma unroll
    for (int j = 0; j < 4; ++j) acc[i][j] = fzero;

  u16* myA = buf + grp * 32768;
  u16* myB = buf + grp * 32768 + 16384;
  const u16* Ab = &ut[((size_t)b * 512 + d0) * 2048 + grp * 1024];
  const u16* Bb = &probs[((size_t)b * 2048 + q0) * 2048 + grp * 1024];
  gemm_core128<16>(Ab, 2048, Bb, 2048, myA, myB, tl, wr, wc, ql, g, acc);

  __syncthreads();
  float* red = (float*)buf;
  if (grp == 1) {
#pragma unroll
    for (int rt = 0; rt < 4; ++rt)
#pragma unroll
      for (int ct = 0; ct < 4; ++ct) {
        int dl = wr * 64 + rt * 16 + g * 4;
        int qlq = wc * 64 + ct * 16 + ql;
#pragma unroll
        for (int r = 0; r < 4; ++r) red[(dl + r) * 128 + qlq] = acc[rt][ct][r];
      }
  }
  __syncthreads();
  if (grp == 0) {
#pragma unroll
    for (int ct = 0; ct < 4; ++ct) {
      int qlq = wc * 64 + ct * 16 + ql;
      int q = q0 + qlq;
      float inv = 1.0f / l[b * 2048 + q];
      size_t orow = ((size_t)b * 2048 + q) * 512;
#pragma unroll
      for (int rt = 0; rt < 4; ++rt) {
        int dl = wr * 64 + rt * 16 + g * 4;
        f4 v;
#pragma unroll
        for (int r = 0; r < 4; ++r) v[r] = acc[rt][ct][r] + red[(dl + r) * 128 + qlq];
        v *= inv;
        *(f4*)&out[orow + d0 + dl] = v;
      }
    }
  }
}

// ---------------------------------------------------------------------------
extern "C" void kernel_launch(void* const* d_in, const int* in_sizes, int n_in,
                              void* d_out, int out_size, void* d_ws, size_t ws_size,
                              hipStream_t stream) {
  const float* x = (const float*)d_in[0];
  const float* Wk = (const float*)d_in[1];
  const float* Wq = (const float*)d_in[2];
  const float* Wv = (const float*)d_in[3];
  const float* Wa = (const float*)d_in[4];
  const float* Wb = (const float*)d_in[5];
  float* out = (float*)d_out;

  char* ws = (char*)d_ws;
  size_t off = 0;
  auto alloc = [&](size_t bytes) -> void* {
    void* p = ws + off;
    off += (bytes + 255) & ~(size_t)255;
    return p;
  };
  u16* wh = (u16*)alloc((size_t)1536 * 1024 * 2);
  u16* xh = (u16*)alloc((size_t)8192 * 1024 * 2);
  u16* kh = (u16*)alloc((size_t)8192 * 512 * 2);
  u16* ph = (u16*)alloc((size_t)8192 * 512 * 2);
  u16* ut = (u16*)alloc((size_t)8192 * 512 * 2);
  u16* probs = (u16*)alloc((size_t)4 * 2048 * 2048 * 2);
  float* l = (float*)alloc(8192 * 4);
  u16* waT_h = (u16*)alloc((size_t)512 * 512 * 2);
  u16* waT_l = (u16*)alloc((size_t)512 * 512 * 2);
  u16* wqT_h = (u16*)alloc((size_t)1024 * 512 * 2);
  u16* wqT_l = (u16*)alloc((size_t)1024 * 512 * 2);
  u16* wb_h = (u16*)alloc((size_t)512 * 512 * 2);
  u16* wb_l = (u16*)alloc((size_t)512 * 512 * 2);
  u16* wvT_h = (u16*)alloc((size_t)1024 * 512 * 2);
  u16* wvT_l = (u16*)alloc((size_t)1024 * 512 * 2);
  (void)ws_size; (void)in_sizes; (void)n_in; (void)out_size;

  hipLaunchKernelGGL(k_prep_w, dim3(1096), dim3(256), 0, stream,
                     Wk, Wq, Wv, Wa, Wb, wh,
                     waT_h, waT_l, wqT_h, wqT_l, wb_h, wb_l, wvT_h, wvT_l, l);
  hipLaunchKernelGGL(k_fx, dim3(8256), dim3(256), 0, stream,
                     x, waT_h, waT_l, wqT_h, wqT_l, wb_h, wb_l, wvT_h, wvT_l,
                     xh, wh);
  hipLaunchKernelGGL(k_proj, dim3(256), dim3(512), 0, stream, xh, wh, kh, ph, ut);
  hipLaunchKernelGGL(k_score, dim3(256), dim3(512), 0, stream, ph, kh, probs, l);
  hipLaunchKernelGGL(k_out, dim3(256), dim3(512), 0, stream, ut, probs, l, out);
}